// Round 9
// baseline (372.648 us; speedup 1.0000x reference)
//
#include <hip/hip_runtime.h>
#include <stdint.h>

typedef unsigned short u16;
typedef __attribute__((ext_vector_type(8))) short bf16x8;
typedef __attribute__((ext_vector_type(4))) float f32x4;

#define MFMA16(a, b, c) __builtin_amdgcn_mfma_f32_16x16x32_bf16(a, b, c, 0, 0, 0)

__device__ __forceinline__ u16 f2bf(float x) {
  union { float f; uint32_t u; } v; v.f = x;
  uint32_t r = (v.u + 0x7FFFu + ((v.u >> 16) & 1u)) >> 16;
  return (u16)r;
}
__device__ __forceinline__ float bf2f(u16 h) {
  union { uint32_t u; float f; } v; v.u = ((uint32_t)h) << 16; return v.f;
}
// packed RNE f32x2 -> bf16x2 (gfx942+ VOP3; low16 = a, high16 = b)
__device__ __forceinline__ uint cvt_pk_bf16(float a, float b) {
  uint r;
  asm("v_cvt_pk_bf16_f32 %0, %1, %2" : "=v"(r) : "v"(a), "v"(b));
  return r;
}
__device__ __forceinline__ void gll16(const void* g, void* s) {
  __builtin_amdgcn_global_load_lds((const __attribute__((address_space(1))) unsigned int*)g,
                                   (__attribute__((address_space(3))) unsigned int*)s, 16, 0, 0);
}

// ---------------- pack kernels ----------------

// merged weight/misc pack, grid 1025 blocks:
//  [0,768):    Wt[z][(n*64+d)*1024 + h] = W[z][n][h][d]
//  [768,1024): Wfct[o*1024 + i] = Wfc[i*1024 + o]
//  1024:       bias concat + pos_k bf16 (144 rows) + pos_v^T bf16 (64x136)
__global__ __launch_bounds__(256) void pack_w_kernel(const float* __restrict__ Wq,
                                                     const float* __restrict__ Wk,
                                                     const float* __restrict__ Wv,
                                                     const float* __restrict__ Wfc,
                                                     const float* __restrict__ bq,
                                                     const float* __restrict__ bk,
                                                     const float* __restrict__ bv,
                                                     const float* __restrict__ posk,
                                                     const float* __restrict__ posv,
                                                     u16* __restrict__ Wt,
                                                     u16* __restrict__ Wfct,
                                                     float* __restrict__ biascat,
                                                     u16* __restrict__ poskbf,
                                                     u16* __restrict__ posvT) {
  __shared__ float tile[64][65];
  const int bi = blockIdx.x;
  if (bi == 1024) {
    for (int i = threadIdx.x; i < 1024; i += 256) {
      biascat[i] = bq[i]; biascat[1024 + i] = bk[i]; biascat[2048 + i] = bv[i];
    }
    for (int i = threadIdx.x; i < 144 * 64; i += 256) {
      int r = i >> 6;
      poskbf[i] = (r < 129) ? f2bf(posk[i]) : (u16)0;
    }
    const int d = threadIdx.x & 63, rr = threadIdx.x >> 6;
#pragma unroll
    for (int j = 0; j < 34; ++j) {
      const int r = rr * 34 + j;
      posvT[d * 136 + r] = (r < 129) ? f2bf(posv[(size_t)r * 64 + d]) : (u16)0;
    }
    return;
  }
  const int r = threadIdx.x >> 2, c0 = (threadIdx.x & 3) * 16;
  const float* src;
  u16* outp;
  if (bi < 768) {
    const int z = bi >> 8, rem = bi & 255, n = rem >> 4, h0 = (rem & 15) * 64;
    const float* W = z == 0 ? Wq : (z == 1 ? Wk : Wv);
    src = W + (size_t)n * 65536 + (size_t)(h0 + r) * 64 + c0;
    outp = Wt + (size_t)z * (1024UL * 1024UL) + (size_t)(n * 64 + r) * 1024 + h0 + c0;
  } else {
    const int t = bi - 768;
    const int i0 = (t & 15) * 64, o0 = (t >> 4) * 64;
    src = Wfc + (size_t)(i0 + r) * 1024 + o0 + c0;
    outp = Wfct + (size_t)(o0 + r) * 1024 + i0 + c0;
  }
#pragma unroll
  for (int j = 0; j < 16; j += 4) {
    float4 f = *(const float4*)(src + j);
    tile[r][c0 + j] = f.x; tile[r][c0 + j + 1] = f.y;
    tile[r][c0 + j + 2] = f.z; tile[r][c0 + j + 3] = f.w;
  }
  __syncthreads();
#pragma unroll
  for (int j = 0; j < 16; ++j) outp[j] = f2bf(tile[c0 + j][r]);
}

// ---------------- GEMM v15: fused pack_x + vtrans, counted-vmcnt pipeline ----------------
// mode 0 (QKV): A read DIRECTLY from fp32 query/key/value. v15: depth-2 A prefetch —
//   two register sets; loadA(t+3) issued at iter t, ds_written at t+2, computed t+3.
//   B (Wt bf16) via global_load_lds, issued at t for compute t+1 (L2-hot: 2MB x 47 reuse).
//   Per-iter sync: vmcnt(8) [leaves newest 8 A-loads in flight; tail: vmcnt(0)],
//   lgkmcnt(0), s_barrier, wrA(t+1), gllB(t+1), loadA(t+3), compute(t).
//   z==0/1 write qkv[bh][1536][64]; z==2 writes Vt directly via LDS-transposed epilogue.
// mode 1 (FC): unchanged v14 path.
// LDS: smem[17408] u16 = 34816 B (loop: bufA 2x4096 + bufB 2x4096; epi: T 128x136).
__global__ __launch_bounds__(256, 4) void gemm_bt_kernel(
    const float* __restrict__ aQ, const float* __restrict__ aK, const float* __restrict__ aV,
    const u16* __restrict__ Ahid,
    const u16* __restrict__ Bbase, long bStride,
    const float* __restrict__ biasBase, long biasStride,
    u16* __restrict__ outBF, u16* __restrict__ VtOut, float* __restrict__ outF, int mode) {
  __shared__ u16 smem[17408];   // As: [buf*4096], Bs: [8192+buf*4096], T: [0..17407]

  // XCD-aware bijective swizzle of the 3D grid (x=8 n-tiles fastest, y=47 m, z)
  const int nwg = 376 * gridDim.z;           // 1128 (qkv) or 376 (fc)
  const int cpx = nwg >> 3;
  const int lid = blockIdx.x + (blockIdx.y << 3) + blockIdx.z * 376;
  const int swz = (lid & 7) * cpx + (lid >> 3);
  const int z = swz / 376;
  const int rem = swz - z * 376;
  const int m0 = (rem >> 3) * 128, n0 = (rem & 7) * 128;

  const u16* Bt = Bbase + (size_t)z * bStride;
  const float* bias = biasBase + (size_t)z * biasStride;
  const int tid = threadIdx.x, w = tid >> 6, lane = tid & 63;
  const int quad = lane >> 4, l16 = lane & 15;
  const int wm = w >> 1, wn = w & 1;
  const int srow = w * 16 + (lane >> 2);
  const int scol = (lane & 3) * 8;

  // B source induction pointers
  const u16* gB0 = Bt + (size_t)(n0 + srow) * 1024 + scol;
  const u16* gB1 = gB0 + 64UL * 1024;
  const int slab = (w * 16) * 32;            // wave's LDS slab offset (u16)

  f32x4 acc[4][4];
  const f32x4 zf = {0.f, 0.f, 0.f, 0.f};
#pragma unroll
  for (int a = 0; a < 4; ++a)
#pragma unroll
    for (int b = 0; b < 4; ++b) acc[a][b] = zf;

  auto gllB = [&](int buf) {
    gll16(gB0, &smem[8192 + buf * 4096 + slab]);
    gll16(gB1, &smem[8192 + buf * 4096 + slab + 64 * 32]);
    gB0 += 32; gB1 += 32;
  };
  auto compute = [&](int buf) {
    bf16x8 af[4], bfr[4];
#pragma unroll
    for (int f = 0; f < 4; ++f) {
      af[f]  = *(const bf16x8*)&smem[buf * 4096 + (wm * 64 + f * 16 + l16) * 32 + quad * 8];
      bfr[f] = *(const bf16x8*)&smem[8192 + buf * 4096 + (wn * 64 + f * 16 + l16) * 32 + quad * 8];
    }
#pragma unroll
    for (int fm = 0; fm < 4; ++fm)
#pragma unroll
      for (int fn = 0; fn < 4; ++fn)
        acc[fm][fn] = MFMA16(af[fm], bfr[fn], acc[fm][fn]);
  };

  if (mode == 0) {
    // ---- fp32 A path (fused pack_x), depth-2 counted-vmcnt pipeline ----
    const float* srcF = z == 0 ? aQ : (z == 1 ? aK : aV);
    int rowA0 = m0 + srow;        if (rowA0 > 5999) rowA0 = 5999;
    int rowA1 = m0 + 64 + srow;   if (rowA1 > 5999) rowA1 = 5999;
    const float* fA0 = srcF + (size_t)rowA0 * 1024 + scol;
    const float* fA1 = srcF + (size_t)rowA1 * 1024 + scol;
    // two register sets; tile parity == set parity
    float4 s0a, s0b, s0c, s0d, s1a, s1b, s1c, s1d;
    auto loadA0 = [&]() {
      s0a = *(const float4*)fA0; s0b = *(const float4*)(fA0 + 4);
      s0c = *(const float4*)fA1; s0d = *(const float4*)(fA1 + 4);
      fA0 += 32; fA1 += 32;
    };
    auto loadA1 = [&]() {
      s1a = *(const float4*)fA0; s1b = *(const float4*)(fA0 + 4);
      s1c = *(const float4*)fA1; s1d = *(const float4*)(fA1 + 4);
      fA0 += 32; fA1 += 32;
    };
    const int adst = (w * 16 + (lane >> 2)) * 32 + (lane & 3) * 8;
    auto wrA = [&](int buf, float4 A0, float4 A1, float4 A2, float4 A3) {
      uint4 lo, hi;
      lo.x = cvt_pk_bf16(A0.x, A0.y); lo.y = cvt_pk_bf16(A0.z, A0.w);
      lo.z = cvt_pk_bf16(A1.x, A1.y); lo.w = cvt_pk_bf16(A1.z, A1.w);
      hi.x = cvt_pk_bf16(A2.x, A2.y); hi.y = cvt_pk_bf16(A2.z, A2.w);
      hi.z = cvt_pk_bf16(A3.x, A3.y); hi.w = cvt_pk_bf16(A3.z, A3.w);
      *(uint4*)&smem[buf * 4096 + adst] = lo;
      *(uint4*)&smem[buf * 4096 + adst + 64 * 32] = hi;
    };

    // prologue: queue = [A(0)x8, B(0)x2, A(1)x8]
    loadA0();            // A(0) -> set0
    gllB(0);             // B(0) -> bufB0
    loadA1();            // A(1) -> set1
    asm volatile("s_waitcnt vmcnt(10)" ::: "memory");   // A(0) landed
    __builtin_amdgcn_sched_barrier(0);
    wrA(0, s0a, s0b, s0c, s0d);   // A(0) -> bufA0
    loadA0();            // A(2) -> set0

#pragma unroll 1
    for (int pr = 0; pr < 16; ++pr) {
      // ---- t = 2pr (even: compute bufA0/bufB0) ----
      if (pr < 15) { asm volatile("s_waitcnt vmcnt(8)" ::: "memory"); }
      else         { asm volatile("s_waitcnt vmcnt(0)" ::: "memory"); }
      asm volatile("s_waitcnt lgkmcnt(0)" ::: "memory");
      __builtin_amdgcn_sched_barrier(0);
      __builtin_amdgcn_s_barrier();
      __builtin_amdgcn_sched_barrier(0);
      wrA(1, s1a, s1b, s1c, s1d);          // A(2pr+1) -> bufA1
      gllB(1);                             // B(2pr+1) -> bufB1
      if (pr < 15) loadA1();               // A(2pr+3) -> set1
      compute(0);
      // ---- t = 2pr+1 (odd: compute bufA1/bufB1) ----
      if (pr < 15) { asm volatile("s_waitcnt vmcnt(8)" ::: "memory"); }
      else         { asm volatile("s_waitcnt vmcnt(0)" ::: "memory"); }
      asm volatile("s_waitcnt lgkmcnt(0)" ::: "memory");
      __builtin_amdgcn_sched_barrier(0);
      __builtin_amdgcn_s_barrier();
      __builtin_amdgcn_sched_barrier(0);
      if (pr < 15) {
        wrA(0, s0a, s0b, s0c, s0d);        // A(2pr+2) -> bufA0
        gllB(0);                           // B(2pr+2) -> bufB0
      }
      if (pr < 14) loadA0();               // A(2pr+4) -> set0
      compute(1);
    }

    if (z < 2) {
      const float scale = (z == 0) ? 0.125f : 1.0f;
      u16* out = outBF + (size_t)z * (4UL * 16 * 1536 * 64);
#pragma unroll
      for (int fm = 0; fm < 4; ++fm) {
#pragma unroll
        for (int i = 0; i < 4; ++i) {
          const int m = m0 + wm * 64 + fm * 16 + quad * 4 + i;
          if (m >= 6000) continue;
          const int bb = m / 1500;
          const int s = m - bb * 1500;
#pragma unroll
          for (int fn = 0; fn < 4; ++fn) {
            const int n = n0 + wn * 64 + fn * 16 + l16;
            const float vv = (acc[fm][fn][i] + bias[n]) * scale;
            const int h = n >> 6, d = n & 63;
            out[((size_t)(bb * 16 + h) * 1536 + s) * 64 + d] = f2bf(vv);
          }
        }
      }
    } else {
      // ---- fused vtrans: write Vt[(bb*16+h)*64+d][1536] via LDS transpose ----
      __syncthreads();   // all waves done with staging LDS
      u16* T = smem;     // [128][136] u16: T[n_local][m_local]
#pragma unroll
      for (int fm = 0; fm < 4; ++fm) {
        const int ml = wm * 64 + fm * 16 + quad * 4;
#pragma unroll
        for (int fn = 0; fn < 4; ++fn) {
          const int nl = wn * 64 + fn * 16 + l16;
          const float b0 = bias[n0 + nl];
          uint2 pk;
          pk.x = cvt_pk_bf16(acc[fm][fn][0] + b0, acc[fm][fn][1] + b0);
          pk.y = cvt_pk_bf16(acc[fm][fn][2] + b0, acc[fm][fn][3] + b0);
          *(uint2*)&T[nl * 136 + ml] = pk;
        }
      }
      __syncthreads();
#pragma unroll 1
      for (int ps = 0; ps < 8; ++ps) {
        const int row = ps * 16 + (tid >> 4);     // n_local
        const int col = (tid & 15) * 8;           // m_local base
        const int ng = n0 + row;
        const int h = ng >> 6, d = ng & 63;
        const int mg = m0 + col;
        uint4 v = *(const uint4*)&T[row * 136 + col];
        const int bb0 = mg / 1500, bb7 = (mg + 7) / 1500;
        if ((bb0 == bb7) & (mg + 7 < 6000)) {
          u16* dst = VtOut + ((size_t)((bb0 * 16 + h) * 64 + d)) * 1536 + (mg - bb0 * 1500);
          uint2 loh; loh.x = v.x; loh.y = v.y;
          uint2 hih; hih.x = v.z; hih.y = v.w;
          *(uint2*)dst = loh;
          *(uint2*)(dst + 4) = hih;
        } else {
          const u16* tv = (const u16*)&v;
#pragma unroll
          for (int j = 0; j < 8; ++j) {
            const int m = mg + j;
            if (m < 6000) {
              const int bb = m / 1500;
              VtOut[((size_t)((bb * 16 + h) * 64 + d)) * 1536 + (m - bb * 1500)] = tv[j];
            }
          }
        }
      }
    }
  } else {
    // ---- mode 1 (FC): bf16 A via DMA (v14 path, unchanged) ----
    const u16* gA0 = Ahid + (size_t)(m0 + srow) * 1024 + scol;
    const u16* gA1 = gA0 + 64UL * 1024;
    auto stage1 = [&](int buf) {
      gll16(gA0, &smem[buf * 4096 + slab]);
      gll16(gA1, &smem[buf * 4096 + slab + 64 * 32]);
      gA0 += 32; gA1 += 32;
      gllB(buf);
    };
    stage1(0);
#define FC_SYNC() do {                                        \
      asm volatile("s_waitcnt vmcnt(0)" ::: "memory");        \
      __builtin_amdgcn_sched_barrier(0);                      \
      __builtin_amdgcn_s_barrier();                           \
      __builtin_amdgcn_sched_barrier(0);                      \
    } while (0)
#pragma unroll 1
    for (int pr = 0; pr < 16; ++pr) {
      FC_SYNC();
      stage1(1);
      compute(0);
      FC_SYNC();
      if (pr < 15) stage1(0);
      compute(1);
    }
#undef FC_SYNC
#pragma unroll
    for (int fm = 0; fm < 4; ++fm) {
#pragma unroll
      for (int i = 0; i < 4; ++i) {
        const int m = m0 + wm * 64 + fm * 16 + quad * 4 + i;
        if (m >= 6000) continue;
#pragma unroll
        for (int fn = 0; fn < 4; ++fn) {
          const int n = n0 + wn * 64 + fn * 16 + l16;
          outF[(size_t)m * 1024 + n] = acc[fm][fn][i] + bias[n];
        }
      }
    }
  }
}

// ---------------- fused attention v12 (unchanged, 89.6 us) ----------------
__global__ __launch_bounds__(256, 4) void attn_kernel(const u16* __restrict__ qkv,
                                                      const u16* __restrict__ Vt,
                                                      const u16* __restrict__ poskbf,
                                                      const u16* __restrict__ posvT,
                                                      const float* __restrict__ posv,
                                                      u16* __restrict__ hidden) {
  const size_t ZS = 4UL * 16 * 1536 * 64;
  __shared__ u16 qb_s[64 * 136];    // merged: qp[q][r] (prologue) -> P histogram [q][delta]
  __shared__ u16 kbuf[2][2048];     // K tile 32 rows x 64 d (row-permuted + chunk-swizzled), dbuf
  __shared__ u16 vbuf[2][2048];     // V^T tile 64 d x 32 k (chunk-swizzled), dbuf

  const int tid = threadIdx.x;
  const int w = tid >> 6, lane = tid & 63, quad = lane >> 4, l16 = lane & 15;
  const int bi = blockIdx.x;
  const int bh = bi & 63;
  const int q0 = (bi >> 6) * 64, qw0 = q0 + w * 16;
  const int b = bh >> 4;
  const size_t sb = (size_t)bh * (1536UL * 64UL);
  const u16* Qp = qkv + sb;
  const u16* Kp = qkv + ZS + sb;
  const u16* Vtb = Vt + (size_t)bh * (64UL * 1536UL);
  u16* qb_row = qb_s + (w * 16 + l16) * 136;   // this lane's row (q = qw0 + l16)

  // staging: wave-uniform LDS base + lane*16B (gll16 contract)
  const int r8 = lane >> 3, c8 = lane & 7;            // K: 8 rows x 8 chunks
  const int vr = lane >> 2, vc = lane & 3;            // V: 16 rows x 4 chunks
  // K row permutation: LDS row p <- global row kp(p) = quad(p)*8 + cg(p)*4 + i(p)
  const int kprow = ((( (w * 8 + r8) & 15) >> 2) * 8) + (((w * 8 + r8) >> 4) * 4) + ((w * 8 + r8) & 3);
  // induction source pointers (advance +2048 / +32 u16 per k-tile)
  const u16* kSrc = Kp + (size_t)kprow * 64 + ((c8 ^ r8) * 8);
  const u16* vSrc = Vtb + (size_t)(w * 16 + vr) * 1536 + ((vc ^ ((vr >> 1) & 3)) * 8);
  u16* const kDst = &kbuf[0][0] + w * 512;   // +2048 for buf1
  u16* const vDst = &vbuf[0][0] + w * 512;

  gll16(kSrc, kDst);
  gll16(vSrc, vDst);

  // Q fragment (rows q = qw0 + l16)
  const u16* qptr = Qp + (size_t)(qw0 + l16) * 64 + quad * 8;
  const bf16x8 qB0 = *(const bf16x8*)qptr;
  const bf16x8 qB1 = *(const bf16x8*)(qptr + 32);

  // qp[q][r] = q . pos_k[r] via MFMA; C layout: row q_loc = quad*4+i, col r = l16
  const f32x4 zf = {0.f, 0.f, 0.f, 0.f};
#pragma unroll
  for (int nf = 0; nf < 9; ++nf) {
    const u16* bp = poskbf + (size_t)(nf * 16 + l16) * 64 + quad * 8;
    bf16x8 b0 = *(const bf16x8*)bp;
    bf16x8 b1 = *(const bf16x8*)(bp + 32);
    f32x4 c = zf;
    c = MFMA16(qB0, b0, c);
    c = MFMA16(qB1, b1, c);
    const int col = nf * 16 + l16;
    if (col < 136) {
#pragma unroll
      for (int i = 0; i < 4; ++i)
        qb_s[(w * 16 + quad * 4 + i) * 136 + col] = f2bf(c[i]);
    }
  }
  __syncthreads();   // qp ready AND buf0 DMA drained

  const float L2E = 1.44269504f;
  const float M8 = -8.0f * L2E;
  const float eLow  = __builtin_fmaf(bf2f(qb_row[0]), L2E, M8);
  const float eHigh = __builtin_fmaf(bf2f(qb_row[128]), L2E, M8);

  f32x4 accf[4];
#pragma unroll
  for (int dc = 0; dc < 4; ++dc) accf[dc] = zf;
  float sSimple = 0.f, sLowSave = 0.f, sDall = 0.f, sD0 = 0.f, sD128 = 0.f;

  const int itLowEnd = (qw0 >= 95) ? (((qw0 - 95) >> 5) + 1) : 0;
  const int itHigh0 = (qw0 + 110) >> 5;
  const int dEnd = itHigh0 < 46 ? itHigh0 : 46;

  const int kswz = (quad ^ (l16 & 7)) * 8;
  const int kswz4 = ((quad + 4) ^ (l16 & 7)) * 8;
  const int vpos = (quad ^ ((l16 >> 1) & 3)) * 8;   // V chunk position after swizzle

  // stage source cursors point at tile it+1
  const u16* kS = kSrc + 2048;
  const u16* vS = vSrc + 32;

  // loop body; kb/vbse/doStage/stageOff are compile-time per call site -> fragment
  // addresses hoist, no runtime buffer select.
  auto body = [&](int it, const u16* kb, const u16* vbse, bool doStage, int stageOff) {
    if (doStage) {
      gll16(kS, kDst + stageOff);
      gll16(vS, vDst + stageOff);
      kS += 2048; vS += 32;
    }

    if (it == itLowEnd) sLowSave = sSimple;
    const int phase = (it < itLowEnd) ? 0 : ((it >= 46) ? 1 : ((it < dEnd) ? 1 : 2));

    // K fragments (row-permuted + chunk-swizzled, conflict-free)
    bf16x8 ka00 = *(const bf16x8*)(kb + l16 * 64 + kswz);
    bf16x8 ka01 = *(const bf16x8*)(kb + l16 * 64 + kswz4);
    bf16x8 ka10 = *(const bf16x8*)(kb + (16 + l16) * 64 + kswz);
    bf16x8 ka11 = *(const bf16x8*)(kb + (16 + l16) * 64 + kswz4);
    // V^T fragments (chunk-swizzled, conflict-free)
    bf16x8 vb0 = *(const bf16x8*)(vbse + l16 * 32 + vpos);
    bf16x8 vb1 = *(const bf16x8*)(vbse + (16 + l16) * 32 + vpos);
    bf16x8 vb2 = *(const bf16x8*)(vbse + (32 + l16) * 32 + vpos);
    bf16x8 vb3 = *(const bf16x8*)(vbse + (48 + l16) * 32 + vpos);

    // diag bias LDS reads (index-only dependence); permuted k: delta = base + quad*8 + cg*4 + i
    float qb[2][4];
    if (phase == 1) {
      const int base = it * 32 + 64 - qw0 - l16 + quad * 8;
#pragma unroll
      for (int cg = 0; cg < 2; ++cg) {
#pragma unroll
        for (int i = 0; i < 4; ++i) {
          int delta = base + cg * 4 + i;
          delta = delta < 0 ? 0 : (delta > 128 ? 128 : delta);
          qb[cg][i] = bf2f(qb_row[delta]);
        }
      }
    }

    f32x4 cc[2];
    cc[0] = zf; cc[1] = zf;
    cc[0] = MFMA16(ka00, qB0, cc[0]);
    cc[0] = MFMA16(ka01, qB1, cc[0]);
    cc[1] = MFMA16(ka10, qB0, cc[1]);
    cc[1] = MFMA16(ka11, qB1, cc[1]);

    float pvv[2][4];
    if (phase != 1) {
      const float eB = (phase == 0) ? eLow : eHigh;
#pragma unroll
      for (int cg = 0; cg < 2; ++cg) {
#pragma unroll
        for (int i = 0; i < 4; ++i) {
          float p = __builtin_amdgcn_exp2f(__builtin_fmaf(cc[cg][i], L2E, eB));
          sSimple += p; pvv[cg][i] = p;
        }
      }
    } else {
      const int kc0 = it * 32;
#pragma unroll
      for (int cg = 0; cg < 2; ++cg) {
        const int krow0 = kc0 + quad * 8 + cg * 4;            // actual k base (permuted)
        const int dbase = krow0 + 64 - qw0 - l16;
#pragma unroll
        for (int i = 0; i < 4; ++i) {
          int delta = dbase + i;
          delta = delta < 0 ? 0 : (delta > 128 ? 128 : delta);
          const float t = cc[cg][i] + qb[cg][i];
          float p = __builtin_amdgcn_exp2f(__builtin_fmaf(t, L2E, M8));
          if (krow0 + i >= 1500) p = 0.f;
          sDall += p;
          sD0   += (delta == 0)   ? p : 0.f;
          sD128 += (delta == 128) ? p : 0.f;
          pvv[cg][i] = p;
        }
        // packed bf16 P stores into the merged buffer (deltas 1..127 only)
        const uint pk01 = cvt_pk_bf16(pvv[cg][0], pvv[cg][1]);
        const uint pk23 = cvt_pk_bf16(pvv[cg][2], pvv[cg][3]);
        const u16 hb[4] = {(u16)pk01, (u16)(pk01 >> 16), (u16)pk23, (u16)(pk23 >> 16)};
#pragma unroll
        for (int i = 0; i < 4; ++i) {
          int delta = dbase + i;
          delta = delta < 0 ? 0 : (delta > 128 ? 128 : delta);
          if ((delta != 0) & (delta != 128)) qb_row[delta] = hb[i];
        }
      }
    }

    // P already in A-fragment order (k = quad*8 + cg*4 + i): just pack to bf16
    union { uint u[4]; bf16x8 v; } pa;
    pa.u[0] = cvt_pk_bf16(pvv[0][0], pvv[0][1]);
    pa.u[1] = cvt_pk_bf16(pvv[0][2], pvv[0][3]);
    pa.u[2] = cvt_pk_bf16(pvv[1][0], pvv[1][1]);
    pa.u[3] = cvt_pk_bf16(pvv[1][2], pvv[1][3]);

    accf[0] = MFMA16(pa.v, vb0, accf[0]);
    accf[1] = MFMA16(pa.v, vb1, accf[1]);
    accf[2] = MFMA16(pa.v, vb2, accf[2]);
    accf[3] = MFMA16(pa.v, vb3, accf[3]);

    __syncthreads();   // drains next-buffer DMA; guards buffer turnover
  };

#pragma unroll 1
  for (int pr = 0; pr < 23; ++pr) {
    const int it0 = pr * 2;
    body(it0,     &kbuf[0][0], &vbuf[0][0], true, 2048);   // cur=0, stage -> buf1
    body(it0 + 1, &kbuf[1][0], &vbuf[1][0], true, 0);      // cur=1, stage -> buf0
  }
  body(46, &kbuf[0][0], &vbuf[0][0], false, 0);

  // reduce softmax state over the 4 quads (q = l16 per lane)
  const float sLow = sLowSave;
  const float sHigh = sSimple - sLowSave;
  float lpart = sSimple + sDall;
  float clow = sLow + sD0;
  float chigh = sHigh + sD128;
#pragma unroll
  for (int m = 16; m <= 32; m <<= 1) {
    lpart += __shfl_xor(lpart, m);
    clow  += __shfl_xor(clow, m);
    chigh += __shfl_xor(chigh, m);
  }
  const float linv = 1.0f / lpart;

  // merged-buffer fixup (wave-private): zero slots the diag pass never wrote so the
  // o2 MFMA sees P=0 there. Row qg: visited slots = [64-qg, 1563-qg] ∩ [1,127];
  // slot 0 always holds qp[0] and must be zeroed. Middle q-tiles: no loop work.
  {
    const int qg_row = qw0 + l16;
    if (quad == 0) qb_row[0] = 0;
    const int lim = 64 - qg_row;              // zero d in [1, lim)
    for (int d = 1 + quad; d < lim; d += 4) qb_row[d] = 0;
    const int dlo = 1564 - qg_row;            // zero d in [dlo, 127]
    for (int d = dlo + quad; d <= 127; d += 4) qb_row[d] = 0;
  }

  // o2 = P[16x128] @ pos_v[128x64] via MFMA (rows wave-private; no barrier needed)
  f32x4 o2[4];
#pragma unroll
  for (int dc = 0; dc < 4; ++dc) o2[dc] = zf;
#pragma unroll
  for (int kk = 0; kk < 4; ++kk) {
    bf16x8 pa2 = *(const bf16x8*)(qb_row + kk * 32 + quad * 8);
#pragma unroll
    for (int dc = 0; dc < 4; ++dc) {
      bf16x8 vb2r = *(const bf16x8*)(posvT + (size_t)(dc * 16 + l16) * 136 + kk * 32 + quad * 8);
      o2[dc] = MFMA16(pa2, vb2r, o2[dc]);
    }
  }

  // per-q scalars live at lane l16=q_loc after butterfly -> shfl from lane q_loc
  float li[4], cl[4], ch[4];
#pragma unroll
  for (int i = 0; i < 4; ++i) {
    const int srcl = quad * 4 + i;
    li[i] = __shfl(linv, srcl);
    cl[i] = __shfl(clow, srcl);
    ch[i] = __shfl(chigh, srcl);
  }

#pragma unroll
  for (int dc = 0; dc < 4; ++dc) {
    const int d = dc * 16 + l16;
    const float pv0 = posv[d], pv1 = posv[128 * 64 + d];
#pragma unroll
    for (int i = 0; i < 4; ++i) {
      const int qg = qw0 + quad * 4 + i;
      if (qg < 1500) {
        const float val = (accf[dc][i] + o2[dc][i] + cl[i] * pv0 + ch[i] * pv1) * li[i];
        hidden[((size_t)(b * 1500 + qg)) * 1024 + (bh & 15) * 64 + d] = f2bf(val);
      }
    }
  }
}

// ---------------- launcher ----------------
extern "C" void kernel_launch(void* const* d_in, const int* in_sizes, int n_in,
                              void* d_out, int out_size, void* d_ws, size_t ws_size,
                              hipStream_t stream) {
  const float* query = (const float*)d_in[0];
  const float* key   = (const float*)d_in[1];
  const float* value = (const float*)d_in[2];
  const float* Wq = (const float*)d_in[3];
  const float* bq = (const float*)d_in[4];
  const float* Wk = (const float*)d_in[5];
  const float* bk = (const float*)d_in[6];
  const float* Wv = (const float*)d_in[7];
  const float* bv = (const float*)d_in[8];
  const float* posk = (const float*)d_in[9];
  const float* posv = (const float*)d_in[10];
  const float* Wfc = (const float*)d_in[11];
  const float* bfc = (const float*)d_in[12];
  float* out = (float*)d_out;

  char* p = (char*)d_ws;
  u16* X = (u16*)p;        p += 3UL * 6016 * 1024 * 2;   // hidden + Vt live here
  u16* Wt = (u16*)p;       p += 3UL * 1024 * 1024 * 2;   // Wq_t,Wk_t,Wv_t
  u16* Wfct = (u16*)p;     p += 1024UL * 1024 * 2;
  u16* poskbf = (u16*)p;   p += 144UL * 64 * 2;
  u16* posvT = (u16*)p;    p += 64UL * 136 * 2;
  float* biascat = (float*)p; p += 3UL * 1024 * 4;
  u16* qkv = (u16*)p;      p += 3UL * 4 * 16 * 1536 * 64 * 2;  // q,k slabs used (v slab idle)
  u16* hidden = X;                       // [6016][1024] bf16
  u16* Vt = X + 6291456;                 // [64*64][1536] bf16

  pack_w_kernel<<<dim3(1025), 256, 0, stream>>>(Wq, Wk, Wv, Wfc, bq, bk, bv, posk, posv,
                                                Wt, Wfct, biascat, poskbf, posvT);

  gemm_bt_kernel<<<dim3(8, 47, 3), 256, 0, stream>>>(
      query, key, value, nullptr, Wt, 1024L * 1024, biascat, 1024L, qkv, Vt, nullptr, 0);

  attn_kernel<<<dim3(1536), 256, 0, stream>>>(qkv, Vt, poskbf, posvT, posv, hidden);

  gemm_bt_kernel<<<dim3(8, 47, 1), 256, 0, stream>>>(
      nullptr, nullptr, nullptr, hidden, Wfct, 0L, bfc, 0L, nullptr, nullptr, out, 1);
}

// Round 10
// 362.183 us; speedup vs baseline: 1.0289x; 1.0289x over previous
//
#include <hip/hip_runtime.h>
#include <stdint.h>

typedef unsigned short u16;
typedef __attribute__((ext_vector_type(8))) short bf16x8;
typedef __attribute__((ext_vector_type(4))) float f32x4;

#define MFMA16(a, b, c) __builtin_amdgcn_mfma_f32_16x16x32_bf16(a, b, c, 0, 0, 0)

__device__ __forceinline__ u16 f2bf(float x) {
  union { float f; uint32_t u; } v; v.f = x;
  uint32_t r = (v.u + 0x7FFFu + ((v.u >> 16) & 1u)) >> 16;
  return (u16)r;
}
__device__ __forceinline__ float bf2f(u16 h) {
  union { uint32_t u; float f; } v; v.u = ((uint32_t)h) << 16; return v.f;
}
// packed RNE f32x2 -> bf16x2 (gfx942+ VOP3; low16 = a, high16 = b)
__device__ __forceinline__ uint cvt_pk_bf16(float a, float b) {
  uint r;
  asm("v_cvt_pk_bf16_f32 %0, %1, %2" : "=v"(r) : "v"(a), "v"(b));
  return r;
}
__device__ __forceinline__ void gll16(const void* g, void* s) {
  __builtin_amdgcn_global_load_lds((const __attribute__((address_space(1))) unsigned int*)g,
                                   (__attribute__((address_space(3))) unsigned int*)s, 16, 0, 0);
}

// ---------------- pack kernels ----------------

// merged weight/misc pack, grid 1025 blocks:
//  [0,768):    Wt[z][(n*64+d)*1024 + h] = W[z][n][h][d]
//  [768,1024): Wfct[o*1024 + i] = Wfc[i*1024 + o]
//  1024:       bias concat + pos_k bf16 (144 rows) + pos_v^T bf16 (64x136)
__global__ __launch_bounds__(256) void pack_w_kernel(const float* __restrict__ Wq,
                                                     const float* __restrict__ Wk,
                                                     const float* __restrict__ Wv,
                                                     const float* __restrict__ Wfc,
                                                     const float* __restrict__ bq,
                                                     const float* __restrict__ bk,
                                                     const float* __restrict__ bv,
                                                     const float* __restrict__ posk,
                                                     const float* __restrict__ posv,
                                                     u16* __restrict__ Wt,
                                                     u16* __restrict__ Wfct,
                                                     float* __restrict__ biascat,
                                                     u16* __restrict__ poskbf,
                                                     u16* __restrict__ posvT) {
  __shared__ float tile[64][65];
  const int bi = blockIdx.x;
  if (bi == 1024) {
    for (int i = threadIdx.x; i < 1024; i += 256) {
      biascat[i] = bq[i]; biascat[1024 + i] = bk[i]; biascat[2048 + i] = bv[i];
    }
    for (int i = threadIdx.x; i < 144 * 64; i += 256) {
      int r = i >> 6;
      poskbf[i] = (r < 129) ? f2bf(posk[i]) : (u16)0;
    }
    const int d = threadIdx.x & 63, rr = threadIdx.x >> 6;
#pragma unroll
    for (int j = 0; j < 34; ++j) {
      const int r = rr * 34 + j;
      posvT[d * 136 + r] = (r < 129) ? f2bf(posv[(size_t)r * 64 + d]) : (u16)0;
    }
    return;
  }
  const int r = threadIdx.x >> 2, c0 = (threadIdx.x & 3) * 16;
  const float* src;
  u16* outp;
  if (bi < 768) {
    const int z = bi >> 8, rem = bi & 255, n = rem >> 4, h0 = (rem & 15) * 64;
    const float* W = z == 0 ? Wq : (z == 1 ? Wk : Wv);
    src = W + (size_t)n * 65536 + (size_t)(h0 + r) * 64 + c0;
    outp = Wt + (size_t)z * (1024UL * 1024UL) + (size_t)(n * 64 + r) * 1024 + h0 + c0;
  } else {
    const int t = bi - 768;
    const int i0 = (t & 15) * 64, o0 = (t >> 4) * 64;
    src = Wfc + (size_t)(i0 + r) * 1024 + o0 + c0;
    outp = Wfct + (size_t)(o0 + r) * 1024 + i0 + c0;
  }
#pragma unroll
  for (int j = 0; j < 16; j += 4) {
    float4 f = *(const float4*)(src + j);
    tile[r][c0 + j] = f.x; tile[r][c0 + j + 1] = f.y;
    tile[r][c0 + j + 2] = f.z; tile[r][c0 + j + 3] = f.w;
  }
  __syncthreads();
#pragma unroll
  for (int j = 0; j < 16; ++j) outp[j] = f2bf(tile[c0 + j][r]);
}

// ---------------- GEMM v16: fused pack_x + vtrans, depth-2 A cover ----------------
// mode 0 (QKV): A read DIRECTLY from fp32 query/key/value. v16 reorder vs v14:
//   loadA(t+1) issued at the TOP of iter t (before the wait), wait is vmcnt(4)
//   (drains A(t) -- loaded one full iteration ago -- and B(t); leaves A(t+1) in
//   flight). wrA/loadA are per-parity by-reference lambdas (v15's by-value float4
//   args caused scratch spills: WRITE_SIZE +25MB). Tail (t=31): no new load, vmcnt(0).
//   z==0/1 write qkv[bh][1536][64]; z==2 writes Vt directly via LDS-transposed epilogue.
// mode 1 (FC): unchanged v14 path.
// LDS: smem[17408] u16 = 34816 B (loop: bufA 2x4096 + bufB 2x4096; epi: T 128x136).
__global__ __launch_bounds__(256, 4) void gemm_bt_kernel(
    const float* __restrict__ aQ, const float* __restrict__ aK, const float* __restrict__ aV,
    const u16* __restrict__ Ahid,
    const u16* __restrict__ Bbase, long bStride,
    const float* __restrict__ biasBase, long biasStride,
    u16* __restrict__ outBF, u16* __restrict__ VtOut, float* __restrict__ outF, int mode) {
  __shared__ u16 smem[17408];   // As: [buf*4096], Bs: [8192+buf*4096], T: [0..17407]

  // XCD-aware bijective swizzle of the 3D grid (x=8 n-tiles fastest, y=47 m, z)
  const int nwg = 376 * gridDim.z;           // 1128 (qkv) or 376 (fc)
  const int cpx = nwg >> 3;
  const int lid = blockIdx.x + (blockIdx.y << 3) + blockIdx.z * 376;
  const int swz = (lid & 7) * cpx + (lid >> 3);
  const int z = swz / 376;
  const int rem = swz - z * 376;
  const int m0 = (rem >> 3) * 128, n0 = (rem & 7) * 128;

  const u16* Bt = Bbase + (size_t)z * bStride;
  const float* bias = biasBase + (size_t)z * biasStride;
  const int tid = threadIdx.x, w = tid >> 6, lane = tid & 63;
  const int quad = lane >> 4, l16 = lane & 15;
  const int wm = w >> 1, wn = w & 1;
  const int srow = w * 16 + (lane >> 2);
  const int scol = (lane & 3) * 8;

  // B source induction pointers
  const u16* gB0 = Bt + (size_t)(n0 + srow) * 1024 + scol;
  const u16* gB1 = gB0 + 64UL * 1024;
  const int slab = (w * 16) * 32;            // wave's LDS slab offset (u16)

  f32x4 acc[4][4];
  const f32x4 zf = {0.f, 0.f, 0.f, 0.f};
#pragma unroll
  for (int a = 0; a < 4; ++a)
#pragma unroll
    for (int b = 0; b < 4; ++b) acc[a][b] = zf;

  auto gllB = [&](int buf) {
    gll16(gB0, &smem[8192 + buf * 4096 + slab]);
    gll16(gB1, &smem[8192 + buf * 4096 + slab + 64 * 32]);
    gB0 += 32; gB1 += 32;
  };
  auto compute = [&](int buf) {
    bf16x8 af[4], bfr[4];
#pragma unroll
    for (int f = 0; f < 4; ++f) {
      af[f]  = *(const bf16x8*)&smem[buf * 4096 + (wm * 64 + f * 16 + l16) * 32 + quad * 8];
      bfr[f] = *(const bf16x8*)&smem[8192 + buf * 4096 + (wn * 64 + f * 16 + l16) * 32 + quad * 8];
    }
#pragma unroll
    for (int fm = 0; fm < 4; ++fm)
#pragma unroll
      for (int fn = 0; fn < 4; ++fn)
        acc[fm][fn] = MFMA16(af[fm], bfr[fn], acc[fm][fn]);
  };

  if (mode == 0) {
    // ---- fp32 A path (fused pack_x), early-issue A with counted vmcnt ----
    const float* srcF = z == 0 ? aQ : (z == 1 ? aK : aV);
    int rowA0 = m0 + srow;        if (rowA0 > 5999) rowA0 = 5999;
    int rowA1 = m0 + 64 + srow;   if (rowA1 > 5999) rowA1 = 5999;
    const float* fA0 = srcF + (size_t)rowA0 * 1024 + scol;
    const float* fA1 = srcF + (size_t)rowA1 * 1024 + scol;
    // two register sets, parity = tile parity; all lambdas capture by reference
    float4 s0a, s0b, s0c, s0d, s1a, s1b, s1c, s1d;
    auto loadA0 = [&]() {
      s0a = *(const float4*)fA0; s0b = *(const float4*)(fA0 + 4);
      s0c = *(const float4*)fA1; s0d = *(const float4*)(fA1 + 4);
      fA0 += 32; fA1 += 32;
    };
    auto loadA1 = [&]() {
      s1a = *(const float4*)fA0; s1b = *(const float4*)(fA0 + 4);
      s1c = *(const float4*)fA1; s1d = *(const float4*)(fA1 + 4);
      fA0 += 32; fA1 += 32;
    };
    const int adst = (w * 16 + (lane >> 2)) * 32 + (lane & 3) * 8;
    auto wrA0 = [&](int buf) {
      uint4 lo, hi;
      lo.x = cvt_pk_bf16(s0a.x, s0a.y); lo.y = cvt_pk_bf16(s0a.z, s0a.w);
      lo.z = cvt_pk_bf16(s0b.x, s0b.y); lo.w = cvt_pk_bf16(s0b.z, s0b.w);
      hi.x = cvt_pk_bf16(s0c.x, s0c.y); hi.y = cvt_pk_bf16(s0c.z, s0c.w);
      hi.z = cvt_pk_bf16(s0d.x, s0d.y); hi.w = cvt_pk_bf16(s0d.z, s0d.w);
      *(uint4*)&smem[buf * 4096 + adst] = lo;
      *(uint4*)&smem[buf * 4096 + adst + 64 * 32] = hi;
    };
    auto wrA1 = [&](int buf) {
      uint4 lo, hi;
      lo.x = cvt_pk_bf16(s1a.x, s1a.y); lo.y = cvt_pk_bf16(s1a.z, s1a.w);
      lo.z = cvt_pk_bf16(s1b.x, s1b.y); lo.w = cvt_pk_bf16(s1b.z, s1b.w);
      hi.x = cvt_pk_bf16(s1c.x, s1c.y); hi.y = cvt_pk_bf16(s1c.z, s1c.w);
      hi.z = cvt_pk_bf16(s1d.x, s1d.y); hi.w = cvt_pk_bf16(s1d.z, s1d.w);
      *(uint4*)&smem[buf * 4096 + adst] = lo;
      *(uint4*)&smem[buf * 4096 + adst + 64 * 32] = hi;
    };

    // prologue: A(0) -> set0, B(0) -> bufB0
    loadA0();
    gllB(0);

#pragma unroll 1
    for (int pr = 0; pr < 16; ++pr) {
      // ---- t = 2pr (compute buf0) ----
      loadA1();                                         // A(2pr+1) -> set1 (early issue)
      asm volatile("s_waitcnt vmcnt(4)" ::: "memory");  // A(2pr) + B(2pr) landed
      __builtin_amdgcn_sched_barrier(0);
      wrA0(0);                                          // A(2pr) -> bufA0
      asm volatile("s_waitcnt lgkmcnt(0)" ::: "memory");
      __builtin_amdgcn_sched_barrier(0);
      __builtin_amdgcn_s_barrier();
      __builtin_amdgcn_sched_barrier(0);
      gllB(1);                                          // B(2pr+1) -> bufB1
      compute(0);
      // ---- t = 2pr+1 (compute buf1) ----
      if (pr < 15) {
        loadA0();                                       // A(2pr+2) -> set0 (early issue)
        asm volatile("s_waitcnt vmcnt(4)" ::: "memory");
      } else {
        asm volatile("s_waitcnt vmcnt(0)" ::: "memory");  // tail: drain A(31)+B(31)
      }
      __builtin_amdgcn_sched_barrier(0);
      wrA1(1);                                          // A(2pr+1) -> bufA1
      asm volatile("s_waitcnt lgkmcnt(0)" ::: "memory");
      __builtin_amdgcn_sched_barrier(0);
      __builtin_amdgcn_s_barrier();
      __builtin_amdgcn_sched_barrier(0);
      if (pr < 15) gllB(0);                             // B(2pr+2) -> bufB0
      compute(1);
    }

    if (z < 2) {
      const float scale = (z == 0) ? 0.125f : 1.0f;
      u16* out = outBF + (size_t)z * (4UL * 16 * 1536 * 64);
#pragma unroll
      for (int fm = 0; fm < 4; ++fm) {
#pragma unroll
        for (int i = 0; i < 4; ++i) {
          const int m = m0 + wm * 64 + fm * 16 + quad * 4 + i;
          if (m >= 6000) continue;
          const int bb = m / 1500;
          const int s = m - bb * 1500;
#pragma unroll
          for (int fn = 0; fn < 4; ++fn) {
            const int n = n0 + wn * 64 + fn * 16 + l16;
            const float vv = (acc[fm][fn][i] + bias[n]) * scale;
            const int h = n >> 6, d = n & 63;
            out[((size_t)(bb * 16 + h) * 1536 + s) * 64 + d] = f2bf(vv);
          }
        }
      }
    } else {
      // ---- fused vtrans: write Vt[(bb*16+h)*64+d][1536] via LDS transpose ----
      __syncthreads();   // all waves done with staging LDS
      u16* T = smem;     // [128][136] u16: T[n_local][m_local]
#pragma unroll
      for (int fm = 0; fm < 4; ++fm) {
        const int ml = wm * 64 + fm * 16 + quad * 4;
#pragma unroll
        for (int fn = 0; fn < 4; ++fn) {
          const int nl = wn * 64 + fn * 16 + l16;
          const float b0 = bias[n0 + nl];
          uint2 pk;
          pk.x = cvt_pk_bf16(acc[fm][fn][0] + b0, acc[fm][fn][1] + b0);
          pk.y = cvt_pk_bf16(acc[fm][fn][2] + b0, acc[fm][fn][3] + b0);
          *(uint2*)&T[nl * 136 + ml] = pk;
        }
      }
      __syncthreads();
#pragma unroll 1
      for (int ps = 0; ps < 8; ++ps) {
        const int row = ps * 16 + (tid >> 4);     // n_local
        const int col = (tid & 15) * 8;           // m_local base
        const int ng = n0 + row;
        const int h = ng >> 6, d = ng & 63;
        const int mg = m0 + col;
        uint4 v = *(const uint4*)&T[row * 136 + col];
        const int bb0 = mg / 1500, bb7 = (mg + 7) / 1500;
        if ((bb0 == bb7) & (mg + 7 < 6000)) {
          u16* dst = VtOut + ((size_t)((bb0 * 16 + h) * 64 + d)) * 1536 + (mg - bb0 * 1500);
          uint2 loh; loh.x = v.x; loh.y = v.y;
          uint2 hih; hih.x = v.z; hih.y = v.w;
          *(uint2*)dst = loh;
          *(uint2*)(dst + 4) = hih;
        } else {
          const u16* tv = (const u16*)&v;
#pragma unroll
          for (int j = 0; j < 8; ++j) {
            const int m = mg + j;
            if (m < 6000) {
              const int bb = m / 1500;
              VtOut[((size_t)((bb * 16 + h) * 64 + d)) * 1536 + (m - bb * 1500)] = tv[j];
            }
          }
        }
      }
    }
  } else {
    // ---- mode 1 (FC): bf16 A via DMA (v14 path, unchanged) ----
    const u16* gA0 = Ahid + (size_t)(m0 + srow) * 1024 + scol;
    const u16* gA1 = gA0 + 64UL * 1024;
    auto stage1 = [&](int buf) {
      gll16(gA0, &smem[buf * 4096 + slab]);
      gll16(gA1, &smem[buf * 4096 + slab + 64 * 32]);
      gA0 += 32; gA1 += 32;
      gllB(buf);
    };
    stage1(0);
#define FC_SYNC() do {                                        \
      asm volatile("s_waitcnt vmcnt(0)" ::: "memory");        \
      __builtin_amdgcn_sched_barrier(0);                      \
      __builtin_amdgcn_s_barrier();                           \
      __builtin_amdgcn_sched_barrier(0);                      \
    } while (0)
#pragma unroll 1
    for (int pr = 0; pr < 16; ++pr) {
      FC_SYNC();
      stage1(1);
      compute(0);
      FC_SYNC();
      if (pr < 15) stage1(0);
      compute(1);
    }
#undef FC_SYNC
#pragma unroll
    for (int fm = 0; fm < 4; ++fm) {
#pragma unroll
      for (int i = 0; i < 4; ++i) {
        const int m = m0 + wm * 64 + fm * 16 + quad * 4 + i;
        if (m >= 6000) continue;
#pragma unroll
        for (int fn = 0; fn < 4; ++fn) {
          const int n = n0 + wn * 64 + fn * 16 + l16;
          outF[(size_t)m * 1024 + n] = acc[fm][fn][i] + bias[n];
        }
      }
    }
  }
}

// ---------------- fused attention v12 (unchanged, 89.6 us) ----------------
__global__ __launch_bounds__(256, 4) void attn_kernel(const u16* __restrict__ qkv,
                                                      const u16* __restrict__ Vt,
                                                      const u16* __restrict__ poskbf,
                                                      const u16* __restrict__ posvT,
                                                      const float* __restrict__ posv,
                                                      u16* __restrict__ hidden) {
  const size_t ZS = 4UL * 16 * 1536 * 64;
  __shared__ u16 qb_s[64 * 136];    // merged: qp[q][r] (prologue) -> P histogram [q][delta]
  __shared__ u16 kbuf[2][2048];     // K tile 32 rows x 64 d (row-permuted + chunk-swizzled), dbuf
  __shared__ u16 vbuf[2][2048];     // V^T tile 64 d x 32 k (chunk-swizzled), dbuf

  const int tid = threadIdx.x;
  const int w = tid >> 6, lane = tid & 63, quad = lane >> 4, l16 = lane & 15;
  const int bi = blockIdx.x;
  const int bh = bi & 63;
  const int q0 = (bi >> 6) * 64, qw0 = q0 + w * 16;
  const int b = bh >> 4;
  const size_t sb = (size_t)bh * (1536UL * 64UL);
  const u16* Qp = qkv + sb;
  const u16* Kp = qkv + ZS + sb;
  const u16* Vtb = Vt + (size_t)bh * (64UL * 1536UL);
  u16* qb_row = qb_s + (w * 16 + l16) * 136;   // this lane's row (q = qw0 + l16)

  // staging: wave-uniform LDS base + lane*16B (gll16 contract)
  const int r8 = lane >> 3, c8 = lane & 7;            // K: 8 rows x 8 chunks
  const int vr = lane >> 2, vc = lane & 3;            // V: 16 rows x 4 chunks
  // K row permutation: LDS row p <- global row kp(p) = quad(p)*8 + cg(p)*4 + i(p)
  const int kprow = ((( (w * 8 + r8) & 15) >> 2) * 8) + (((w * 8 + r8) >> 4) * 4) + ((w * 8 + r8) & 3);
  // induction source pointers (advance +2048 / +32 u16 per k-tile)
  const u16* kSrc = Kp + (size_t)kprow * 64 + ((c8 ^ r8) * 8);
  const u16* vSrc = Vtb + (size_t)(w * 16 + vr) * 1536 + ((vc ^ ((vr >> 1) & 3)) * 8);
  u16* const kDst = &kbuf[0][0] + w * 512;   // +2048 for buf1
  u16* const vDst = &vbuf[0][0] + w * 512;

  gll16(kSrc, kDst);
  gll16(vSrc, vDst);

  // Q fragment (rows q = qw0 + l16)
  const u16* qptr = Qp + (size_t)(qw0 + l16) * 64 + quad * 8;
  const bf16x8 qB0 = *(const bf16x8*)qptr;
  const bf16x8 qB1 = *(const bf16x8*)(qptr + 32);

  // qp[q][r] = q . pos_k[r] via MFMA; C layout: row q_loc = quad*4+i, col r = l16
  const f32x4 zf = {0.f, 0.f, 0.f, 0.f};
#pragma unroll
  for (int nf = 0; nf < 9; ++nf) {
    const u16* bp = poskbf + (size_t)(nf * 16 + l16) * 64 + quad * 8;
    bf16x8 b0 = *(const bf16x8*)bp;
    bf16x8 b1 = *(const bf16x8*)(bp + 32);
    f32x4 c = zf;
    c = MFMA16(qB0, b0, c);
    c = MFMA16(qB1, b1, c);
    const int col = nf * 16 + l16;
    if (col < 136) {
#pragma unroll
      for (int i = 0; i < 4; ++i)
        qb_s[(w * 16 + quad * 4 + i) * 136 + col] = f2bf(c[i]);
    }
  }
  __syncthreads();   // qp ready AND buf0 DMA drained

  const float L2E = 1.44269504f;
  const float M8 = -8.0f * L2E;
  const float eLow  = __builtin_fmaf(bf2f(qb_row[0]), L2E, M8);
  const float eHigh = __builtin_fmaf(bf2f(qb_row[128]), L2E, M8);

  f32x4 accf[4];
#pragma unroll
  for (int dc = 0; dc < 4; ++dc) accf[dc] = zf;
  float sSimple = 0.f, sLowSave = 0.f, sDall = 0.f, sD0 = 0.f, sD128 = 0.f;

  const int itLowEnd = (qw0 >= 95) ? (((qw0 - 95) >> 5) + 1) : 0;
  const int itHigh0 = (qw0 + 110) >> 5;
  const int dEnd = itHigh0 < 46 ? itHigh0 : 46;

  const int kswz = (quad ^ (l16 & 7)) * 8;
  const int kswz4 = ((quad + 4) ^ (l16 & 7)) * 8;
  const int vpos = (quad ^ ((l16 >> 1) & 3)) * 8;   // V chunk position after swizzle

  // stage source cursors point at tile it+1
  const u16* kS = kSrc + 2048;
  const u16* vS = vSrc + 32;

  // loop body; kb/vbse/doStage/stageOff are compile-time per call site -> fragment
  // addresses hoist, no runtime buffer select.
  auto body = [&](int it, const u16* kb, const u16* vbse, bool doStage, int stageOff) {
    if (doStage) {
      gll16(kS, kDst + stageOff);
      gll16(vS, vDst + stageOff);
      kS += 2048; vS += 32;
    }

    if (it == itLowEnd) sLowSave = sSimple;
    const int phase = (it < itLowEnd) ? 0 : ((it >= 46) ? 1 : ((it < dEnd) ? 1 : 2));

    // K fragments (row-permuted + chunk-swizzled, conflict-free)
    bf16x8 ka00 = *(const bf16x8*)(kb + l16 * 64 + kswz);
    bf16x8 ka01 = *(const bf16x8*)(kb + l16 * 64 + kswz4);
    bf16x8 ka10 = *(const bf16x8*)(kb + (16 + l16) * 64 + kswz);
    bf16x8 ka11 = *(const bf16x8*)(kb + (16 + l16) * 64 + kswz4);
    // V^T fragments (chunk-swizzled, conflict-free)
    bf16x8 vb0 = *(const bf16x8*)(vbse + l16 * 32 + vpos);
    bf16x8 vb1 = *(const bf16x8*)(vbse + (16 + l16) * 32 + vpos);
    bf16x8 vb2 = *(const bf16x8*)(vbse + (32 + l16) * 32 + vpos);
    bf16x8 vb3 = *(const bf16x8*)(vbse + (48 + l16) * 32 + vpos);

    // diag bias LDS reads (index-only dependence); permuted k: delta = base + quad*8 + cg*4 + i
    float qb[2][4];
    if (phase == 1) {
      const int base = it * 32 + 64 - qw0 - l16 + quad * 8;
#pragma unroll
      for (int cg = 0; cg < 2; ++cg) {
#pragma unroll
        for (int i = 0; i < 4; ++i) {
          int delta = base + cg * 4 + i;
          delta = delta < 0 ? 0 : (delta > 128 ? 128 : delta);
          qb[cg][i] = bf2f(qb_row[delta]);
        }
      }
    }

    f32x4 cc[2];
    cc[0] = zf; cc[1] = zf;
    cc[0] = MFMA16(ka00, qB0, cc[0]);
    cc[0] = MFMA16(ka01, qB1, cc[0]);
    cc[1] = MFMA16(ka10, qB0, cc[1]);
    cc[1] = MFMA16(ka11, qB1, cc[1]);

    float pvv[2][4];
    if (phase != 1) {
      const float eB = (phase == 0) ? eLow : eHigh;
#pragma unroll
      for (int cg = 0; cg < 2; ++cg) {
#pragma unroll
        for (int i = 0; i < 4; ++i) {
          float p = __builtin_amdgcn_exp2f(__builtin_fmaf(cc[cg][i], L2E, eB));
          sSimple += p; pvv[cg][i] = p;
        }
      }
    } else {
      const int kc0 = it * 32;
#pragma unroll
      for (int cg = 0; cg < 2; ++cg) {
        const int krow0 = kc0 + quad * 8 + cg * 4;            // actual k base (permuted)
        const int dbase = krow0 + 64 - qw0 - l16;
#pragma unroll
        for (int i = 0; i < 4; ++i) {
          int delta = dbase + i;
          delta = delta < 0 ? 0 : (delta > 128 ? 128 : delta);
          const float t = cc[cg][i] + qb[cg][i];
          float p = __builtin_amdgcn_exp2f(__builtin_fmaf(t, L2E, M8));
          if (krow0 + i >= 1500) p = 0.f;
          sDall += p;
          sD0   += (delta == 0)   ? p : 0.f;
          sD128 += (delta == 128) ? p : 0.f;
          pvv[cg][i] = p;
        }
        // packed bf16 P stores into the merged buffer (deltas 1..127 only)
        const uint pk01 = cvt_pk_bf16(pvv[cg][0], pvv[cg][1]);
        const uint pk23 = cvt_pk_bf16(pvv[cg][2], pvv[cg][3]);
        const u16 hb[4] = {(u16)pk01, (u16)(pk01 >> 16), (u16)pk23, (u16)(pk23 >> 16)};
#pragma unroll
        for (int i = 0; i < 4; ++i) {
          int delta = dbase + i;
          delta = delta < 0 ? 0 : (delta > 128 ? 128 : delta);
          if ((delta != 0) & (delta != 128)) qb_row[delta] = hb[i];
        }
      }
    }

    // P already in A-fragment order (k = quad*8 + cg*4 + i): just pack to bf16
    union { uint u[4]; bf16x8 v; } pa;
    pa.u[0] = cvt_pk_bf16(pvv[0][0], pvv[0][1]);
    pa.u[1] = cvt_pk_bf16(pvv[0][2], pvv[0][3]);
    pa.u[2] = cvt_pk_bf16(pvv[1][0], pvv[1][1]);
    pa.u[3] = cvt_pk_bf16(pvv[1][2], pvv[1][3]);

    accf[0] = MFMA16(pa.v, vb0, accf[0]);
    accf[1] = MFMA16(pa.v, vb1, accf[1]);
    accf[2] = MFMA16(pa.v, vb2, accf[2]);
    accf[3] = MFMA16(pa.v, vb3, accf[3]);

    __syncthreads();   // drains next-buffer DMA; guards buffer turnover
  };

#pragma unroll 1
  for (int pr = 0; pr < 23; ++pr) {
    const int it0 = pr * 2;
    body(it0,     &kbuf[0][0], &vbuf[0][0], true, 2048);   // cur=0, stage -> buf1
    body(it0 + 1, &kbuf[1][0], &vbuf[1][0], true, 0);      // cur=1, stage -> buf0
  }
  body(46, &kbuf[0][0], &vbuf[0][0], false, 0);

  // reduce softmax state over the 4 quads (q = l16 per lane)
  const float sLow = sLowSave;
  const float sHigh = sSimple - sLowSave;
  float lpart = sSimple + sDall;
  float clow = sLow + sD0;
  float chigh = sHigh + sD128;
#pragma unroll
  for (int m = 16; m <= 32; m <<= 1) {
    lpart += __shfl_xor(lpart, m);
    clow  += __shfl_xor(clow, m);
    chigh += __shfl_xor(chigh, m);
  }
  const float linv = 1.0f / lpart;

  // merged-buffer fixup (wave-private): zero slots the diag pass never wrote so the
  // o2 MFMA sees P=0 there. Row qg: visited slots = [64-qg, 1563-qg] ∩ [1,127];
  // slot 0 always holds qp[0] and must be zeroed. Middle q-tiles: no loop work.
  {
    const int qg_row = qw0 + l16;
    if (quad == 0) qb_row[0] = 0;
    const int lim = 64 - qg_row;              // zero d in [1, lim)
    for (int d = 1 + quad; d < lim; d += 4) qb_row[d] = 0;
    const int dlo = 1564 - qg_row;            // zero d in [dlo, 127]
    for (int d = dlo + quad; d <= 127; d += 4) qb_row[d] = 0;
  }

  // o2 = P[16x128] @ pos_v[128x64] via MFMA (rows wave-private; no barrier needed)
  f32x4 o2[4];
#pragma unroll
  for (int dc = 0; dc < 4; ++dc) o2[dc] = zf;
#pragma unroll
  for (int kk = 0; kk < 4; ++kk) {
    bf16x8 pa2 = *(const bf16x8*)(qb_row + kk * 32 + quad * 8);
#pragma unroll
    for (int dc = 0; dc < 4; ++dc) {
      bf16x8 vb2r = *(const bf16x8*)(posvT + (size_t)(dc * 16 + l16) * 136 + kk * 32 + quad * 8);
      o2[dc] = MFMA16(pa2, vb2r, o2[dc]);
    }
  }

  // per-q scalars live at lane l16=q_loc after butterfly -> shfl from lane q_loc
  float li[4], cl[4], ch[4];
#pragma unroll
  for (int i = 0; i < 4; ++i) {
    const int srcl = quad * 4 + i;
    li[i] = __shfl(linv, srcl);
    cl[i] = __shfl(clow, srcl);
    ch[i] = __shfl(chigh, srcl);
  }

#pragma unroll
  for (int dc = 0; dc < 4; ++dc) {
    const int d = dc * 16 + l16;
    const float pv0 = posv[d], pv1 = posv[128 * 64 + d];
#pragma unroll
    for (int i = 0; i < 4; ++i) {
      const int qg = qw0 + quad * 4 + i;
      if (qg < 1500) {
        const float val = (accf[dc][i] + o2[dc][i] + cl[i] * pv0 + ch[i] * pv1) * li[i];
        hidden[((size_t)(b * 1500 + qg)) * 1024 + (bh & 15) * 64 + d] = f2bf(val);
      }
    }
  }
}

// ---------------- launcher ----------------
extern "C" void kernel_launch(void* const* d_in, const int* in_sizes, int n_in,
                              void* d_out, int out_size, void* d_ws, size_t ws_size,
                              hipStream_t stream) {
  const float* query = (const float*)d_in[0];
  const float* key   = (const float*)d_in[1];
  const float* value = (const float*)d_in[2];
  const float* Wq = (const float*)d_in[3];
  const float* bq = (const float*)d_in[4];
  const float* Wk = (const float*)d_in[5];
  const float* bk = (const float*)d_in[6];
  const float* Wv = (const float*)d_in[7];
  const float* bv = (const float*)d_in[8];
  const float* posk = (const float*)d_in[9];
  const float* posv = (const float*)d_in[10];
  const float* Wfc = (const float*)d_in[11];
  const float* bfc = (const float*)d_in[12];
  float* out = (float*)d_out;

  char* p = (char*)d_ws;
  u16* X = (u16*)p;        p += 3UL * 6016 * 1024 * 2;   // hidden + Vt live here
  u16* Wt = (u16*)p;       p += 3UL * 1024 * 1024 * 2;   // Wq_t,Wk_t,Wv_t
  u16* Wfct = (u16*)p;     p += 1024UL * 1024 * 2;
  u16* poskbf = (u16*)p;   p += 144UL * 64 * 2;
  u16* posvT = (u16*)p;    p += 64UL * 136 * 2;
  float* biascat = (float*)p; p += 3UL * 1024 * 4;
  u16* qkv = (u16*)p;      p += 3UL * 4 * 16 * 1536 * 64 * 2;  // q,k slabs used (v slab idle)
  u16* hidden = X;                       // [6016][1024] bf16
  u16* Vt = X + 6291456;                 // [64*64][1536] bf16

  pack_w_kernel<<<dim3(1025), 256, 0, stream>>>(Wq, Wk, Wv, Wfc, bq, bk, bv, posk, posv,
                                                Wt, Wfct, biascat, poskbf, posvT);

  gemm_bt_kernel<<<dim3(8, 47, 3), 256, 0, stream>>>(
      query, key, value, nullptr, Wt, 1024L * 1024, biascat, 1024L, qkv, Vt, nullptr, 0);

  attn_kernel<<<dim3(1536), 256, 0, stream>>>(qkv, Vt, poskbf, posvT, posv, hidden);

  gemm_bt_kernel<<<dim3(8, 47, 1), 256, 0, stream>>>(
      nullptr, nullptr, nullptr, hidden, Wfct, 0L, bfc, 0L, nullptr, nullptr, out, 1);
}

// Round 11
// 346.223 us; speedup vs baseline: 1.0763x; 1.0461x over previous
//
#include <hip/hip_runtime.h>
#include <stdint.h>

typedef unsigned short u16;
typedef __attribute__((ext_vector_type(8))) short bf16x8;
typedef __attribute__((ext_vector_type(4))) float f32x4;

#define MFMA16(a, b, c) __builtin_amdgcn_mfma_f32_16x16x32_bf16(a, b, c, 0, 0, 0)

__device__ __forceinline__ u16 f2bf(float x) {
  union { float f; uint32_t u; } v; v.f = x;
  uint32_t r = (v.u + 0x7FFFu + ((v.u >> 16) & 1u)) >> 16;
  return (u16)r;
}
__device__ __forceinline__ float bf2f(u16 h) {
  union { uint32_t u; float f; } v; v.u = ((uint32_t)h) << 16; return v.f;
}
// packed RNE f32x2 -> bf16x2 (gfx942+ VOP3; low16 = a, high16 = b)
__device__ __forceinline__ uint cvt_pk_bf16(float a, float b) {
  uint r;
  asm("v_cvt_pk_bf16_f32 %0, %1, %2" : "=v"(r) : "v"(a), "v"(b));
  return r;
}
__device__ __forceinline__ void gll16(const void* g, void* s) {
  __builtin_amdgcn_global_load_lds((const __attribute__((address_space(1))) unsigned int*)g,
                                   (__attribute__((address_space(3))) unsigned int*)s, 16, 0, 0);
}

// ---------------- pack kernels ----------------

// merged weight/misc pack, grid 1025 blocks:
//  [0,768):    Wt[z][(n*64+d)*1024 + h] = W[z][n][h][d]
//  [768,1024): Wfct[o*1024 + i] = Wfc[i*1024 + o]
//  1024:       bias concat + pos_k bf16 (144 rows) + pos_v^T bf16 (64x136)
__global__ __launch_bounds__(256) void pack_w_kernel(const float* __restrict__ Wq,
                                                     const float* __restrict__ Wk,
                                                     const float* __restrict__ Wv,
                                                     const float* __restrict__ Wfc,
                                                     const float* __restrict__ bq,
                                                     const float* __restrict__ bk,
                                                     const float* __restrict__ bv,
                                                     const float* __restrict__ posk,
                                                     const float* __restrict__ posv,
                                                     u16* __restrict__ Wt,
                                                     u16* __restrict__ Wfct,
                                                     float* __restrict__ biascat,
                                                     u16* __restrict__ poskbf,
                                                     u16* __restrict__ posvT) {
  __shared__ float tile[64][65];
  const int bi = blockIdx.x;
  if (bi == 1024) {
    for (int i = threadIdx.x; i < 1024; i += 256) {
      biascat[i] = bq[i]; biascat[1024 + i] = bk[i]; biascat[2048 + i] = bv[i];
    }
    for (int i = threadIdx.x; i < 144 * 64; i += 256) {
      int r = i >> 6;
      poskbf[i] = (r < 129) ? f2bf(posk[i]) : (u16)0;
    }
    const int d = threadIdx.x & 63, rr = threadIdx.x >> 6;
#pragma unroll
    for (int j = 0; j < 34; ++j) {
      const int r = rr * 34 + j;
      posvT[d * 136 + r] = (r < 129) ? f2bf(posv[(size_t)r * 64 + d]) : (u16)0;
    }
    return;
  }
  const int r = threadIdx.x >> 2, c0 = (threadIdx.x & 3) * 16;
  const float* src;
  u16* outp;
  if (bi < 768) {
    const int z = bi >> 8, rem = bi & 255, n = rem >> 4, h0 = (rem & 15) * 64;
    const float* W = z == 0 ? Wq : (z == 1 ? Wk : Wv);
    src = W + (size_t)n * 65536 + (size_t)(h0 + r) * 64 + c0;
    outp = Wt + (size_t)z * (1024UL * 1024UL) + (size_t)(n * 64 + r) * 1024 + h0 + c0;
  } else {
    const int t = bi - 768;
    const int i0 = (t & 15) * 64, o0 = (t >> 4) * 64;
    src = Wfc + (size_t)(i0 + r) * 1024 + o0 + c0;
    outp = Wfct + (size_t)(o0 + r) * 1024 + i0 + c0;
  }
#pragma unroll
  for (int j = 0; j < 16; j += 4) {
    float4 f = *(const float4*)(src + j);
    tile[r][c0 + j] = f.x; tile[r][c0 + j + 1] = f.y;
    tile[r][c0 + j + 2] = f.z; tile[r][c0 + j + 3] = f.w;
  }
  __syncthreads();
#pragma unroll
  for (int j = 0; j < 16; ++j) outp[j] = f2bf(tile[c0 + j][r]);
}

// ---------------- GEMM v17: fused pack_x + vtrans, early A-issue (zero extra regs) ----
// mode 0 (QKV): A read DIRECTLY from fp32 query/key/value, ONE register set.
//   v17 vs v14 (the 102.7us best): loadA(t+1) issued RIGHT AFTER wrA(t) (the set is
//   dead after the ds_write), i.e. BEFORE the barrier. A(t+1)'s latency is covered by
//   lgkm + barrier-wait + gllB + compute(t) instead of compute(t) only. No second
//   register set (v15/v16's dual-set schemes spilled at the 64-VGPR allocation).
//   z==0/1 write qkv[bh][1536][64]; z==2 writes Vt directly via LDS-transposed epilogue.
// mode 1 (FC): unchanged v14 path.
// LDS: smem[17408] u16 = 34816 B (loop: bufA 2x4096 + bufB 2x4096; epi: T 128x136).
__global__ __launch_bounds__(256, 4) void gemm_bt_kernel(
    const float* __restrict__ aQ, const float* __restrict__ aK, const float* __restrict__ aV,
    const u16* __restrict__ Ahid,
    const u16* __restrict__ Bbase, long bStride,
    const float* __restrict__ biasBase, long biasStride,
    u16* __restrict__ outBF, u16* __restrict__ VtOut, float* __restrict__ outF, int mode) {
  __shared__ u16 smem[17408];   // As: [buf*4096], Bs: [8192+buf*4096], T: [0..17407]

  // XCD-aware bijective swizzle of the 3D grid (x=8 n-tiles fastest, y=47 m, z)
  const int nwg = 376 * gridDim.z;           // 1128 (qkv) or 376 (fc)
  const int cpx = nwg >> 3;
  const int lid = blockIdx.x + (blockIdx.y << 3) + blockIdx.z * 376;
  const int swz = (lid & 7) * cpx + (lid >> 3);
  const int z = swz / 376;
  const int rem = swz - z * 376;
  const int m0 = (rem >> 3) * 128, n0 = (rem & 7) * 128;

  const u16* Bt = Bbase + (size_t)z * bStride;
  const float* bias = biasBase + (size_t)z * biasStride;
  const int tid = threadIdx.x, w = tid >> 6, lane = tid & 63;
  const int quad = lane >> 4, l16 = lane & 15;
  const int wm = w >> 1, wn = w & 1;
  const int srow = w * 16 + (lane >> 2);
  const int scol = (lane & 3) * 8;

  // B source induction pointers
  const u16* gB0 = Bt + (size_t)(n0 + srow) * 1024 + scol;
  const u16* gB1 = gB0 + 64UL * 1024;
  const int slab = (w * 16) * 32;            // wave's LDS slab offset (u16)

  f32x4 acc[4][4];
  const f32x4 zf = {0.f, 0.f, 0.f, 0.f};
#pragma unroll
  for (int a = 0; a < 4; ++a)
#pragma unroll
    for (int b = 0; b < 4; ++b) acc[a][b] = zf;

  auto gllB = [&](int buf) {
    gll16(gB0, &smem[8192 + buf * 4096 + slab]);
    gll16(gB1, &smem[8192 + buf * 4096 + slab + 64 * 32]);
    gB0 += 32; gB1 += 32;
  };
  auto compute = [&](int buf) {
    bf16x8 af[4], bfr[4];
#pragma unroll
    for (int f = 0; f < 4; ++f) {
      af[f]  = *(const bf16x8*)&smem[buf * 4096 + (wm * 64 + f * 16 + l16) * 32 + quad * 8];
      bfr[f] = *(const bf16x8*)&smem[8192 + buf * 4096 + (wn * 64 + f * 16 + l16) * 32 + quad * 8];
    }
#pragma unroll
    for (int fm = 0; fm < 4; ++fm)
#pragma unroll
      for (int fn = 0; fn < 4; ++fn)
        acc[fm][fn] = MFMA16(af[fm], bfr[fn], acc[fm][fn]);
  };

  if (mode == 0) {
    // ---- fp32 A path (fused pack_x), single reg set, early issue after wrA ----
    const float* srcF = z == 0 ? aQ : (z == 1 ? aK : aV);
    int rowA0 = m0 + srow;        if (rowA0 > 5999) rowA0 = 5999;
    int rowA1 = m0 + 64 + srow;   if (rowA1 > 5999) rowA1 = 5999;
    const float* fA0 = srcF + (size_t)rowA0 * 1024 + scol;
    const float* fA1 = srcF + (size_t)rowA1 * 1024 + scol;
    float4 a00, a01, a10, a11;
    auto loadA = [&]() {
      a00 = *(const float4*)fA0; a01 = *(const float4*)(fA0 + 4);
      a10 = *(const float4*)fA1; a11 = *(const float4*)(fA1 + 4);
      fA0 += 32; fA1 += 32;
    };
    const int adst = (w * 16 + (lane >> 2)) * 32 + (lane & 3) * 8;
    auto wrA = [&](int buf) {
      uint4 lo, hi;
      lo.x = cvt_pk_bf16(a00.x, a00.y); lo.y = cvt_pk_bf16(a00.z, a00.w);
      lo.z = cvt_pk_bf16(a01.x, a01.y); lo.w = cvt_pk_bf16(a01.z, a01.w);
      hi.x = cvt_pk_bf16(a10.x, a10.y); hi.y = cvt_pk_bf16(a10.z, a10.w);
      hi.z = cvt_pk_bf16(a11.x, a11.y); hi.w = cvt_pk_bf16(a11.z, a11.w);
      *(uint4*)&smem[buf * 4096 + adst] = lo;
      *(uint4*)&smem[buf * 4096 + adst + 64 * 32] = hi;
    };

    loadA();          // A(0) -> regs
    gllB(0);          // B(0) -> bufB0

    // per-iter: vmcnt(0) [A(t) regs + B(t) LDS landed]; wrA(t); loadA(t+1)  <-- regs
    // just freed, issued BEFORE the barrier so barrier-wait covers its latency;
    // lgkm(0); barrier; gllB(t+1); compute(t).
#pragma unroll 1
    for (int pr = 0; pr < 16; ++pr) {
      // ---- t = 2pr (compute buf0) ----
      asm volatile("s_waitcnt vmcnt(0)" ::: "memory");
      __builtin_amdgcn_sched_barrier(0);
      wrA(0);                                           // A(2pr) -> bufA0
      loadA();                                          // A(2pr+1) (early issue)
      asm volatile("s_waitcnt lgkmcnt(0)" ::: "memory");
      __builtin_amdgcn_sched_barrier(0);
      __builtin_amdgcn_s_barrier();
      __builtin_amdgcn_sched_barrier(0);
      gllB(1);                                          // B(2pr+1) -> bufB1
      compute(0);
      // ---- t = 2pr+1 (compute buf1) ----
      asm volatile("s_waitcnt vmcnt(0)" ::: "memory");
      __builtin_amdgcn_sched_barrier(0);
      wrA(1);                                           // A(2pr+1) -> bufA1
      if (pr < 15) loadA();                             // A(2pr+2) (early issue)
      asm volatile("s_waitcnt lgkmcnt(0)" ::: "memory");
      __builtin_amdgcn_sched_barrier(0);
      __builtin_amdgcn_s_barrier();
      __builtin_amdgcn_sched_barrier(0);
      if (pr < 15) gllB(0);                             // B(2pr+2) -> bufB0
      compute(1);
    }

    if (z < 2) {
      const float scale = (z == 0) ? 0.125f : 1.0f;
      u16* out = outBF + (size_t)z * (4UL * 16 * 1536 * 64);
#pragma unroll
      for (int fm = 0; fm < 4; ++fm) {
#pragma unroll
        for (int i = 0; i < 4; ++i) {
          const int m = m0 + wm * 64 + fm * 16 + quad * 4 + i;
          if (m >= 6000) continue;
          const int bb = m / 1500;
          const int s = m - bb * 1500;
#pragma unroll
          for (int fn = 0; fn < 4; ++fn) {
            const int n = n0 + wn * 64 + fn * 16 + l16;
            const float vv = (acc[fm][fn][i] + bias[n]) * scale;
            const int h = n >> 6, d = n & 63;
            out[((size_t)(bb * 16 + h) * 1536 + s) * 64 + d] = f2bf(vv);
          }
        }
      }
    } else {
      // ---- fused vtrans: write Vt[(bb*16+h)*64+d][1536] via LDS transpose ----
      __syncthreads();   // all waves done with staging LDS
      u16* T = smem;     // [128][136] u16: T[n_local][m_local]
#pragma unroll
      for (int fm = 0; fm < 4; ++fm) {
        const int ml = wm * 64 + fm * 16 + quad * 4;
#pragma unroll
        for (int fn = 0; fn < 4; ++fn) {
          const int nl = wn * 64 + fn * 16 + l16;
          const float b0 = bias[n0 + nl];
          uint2 pk;
          pk.x = cvt_pk_bf16(acc[fm][fn][0] + b0, acc[fm][fn][1] + b0);
          pk.y = cvt_pk_bf16(acc[fm][fn][2] + b0, acc[fm][fn][3] + b0);
          *(uint2*)&T[nl * 136 + ml] = pk;
        }
      }
      __syncthreads();
#pragma unroll 1
      for (int ps = 0; ps < 8; ++ps) {
        const int row = ps * 16 + (tid >> 4);     // n_local
        const int col = (tid & 15) * 8;           // m_local base
        const int ng = n0 + row;
        const int h = ng >> 6, d = ng & 63;
        const int mg = m0 + col;
        uint4 v = *(const uint4*)&T[row * 136 + col];
        const int bb0 = mg / 1500, bb7 = (mg + 7) / 1500;
        if ((bb0 == bb7) & (mg + 7 < 6000)) {
          u16* dst = VtOut + ((size_t)((bb0 * 16 + h) * 64 + d)) * 1536 + (mg - bb0 * 1500);
          uint2 loh; loh.x = v.x; loh.y = v.y;
          uint2 hih; hih.x = v.z; hih.y = v.w;
          *(uint2*)dst = loh;
          *(uint2*)(dst + 4) = hih;
        } else {
          const u16* tv = (const u16*)&v;
#pragma unroll
          for (int j = 0; j < 8; ++j) {
            const int m = mg + j;
            if (m < 6000) {
              const int bb = m / 1500;
              VtOut[((size_t)((bb * 16 + h) * 64 + d)) * 1536 + (m - bb * 1500)] = tv[j];
            }
          }
        }
      }
    }
  } else {
    // ---- mode 1 (FC): bf16 A via DMA (v14 path, unchanged) ----
    const u16* gA0 = Ahid + (size_t)(m0 + srow) * 1024 + scol;
    const u16* gA1 = gA0 + 64UL * 1024;
    auto stage1 = [&](int buf) {
      gll16(gA0, &smem[buf * 4096 + slab]);
      gll16(gA1, &smem[buf * 4096 + slab + 64 * 32]);
      gA0 += 32; gA1 += 32;
      gllB(buf);
    };
    stage1(0);
#define FC_SYNC() do {                                        \
      asm volatile("s_waitcnt vmcnt(0)" ::: "memory");        \
      __builtin_amdgcn_sched_barrier(0);                      \
      __builtin_amdgcn_s_barrier();                           \
      __builtin_amdgcn_sched_barrier(0);                      \
    } while (0)
#pragma unroll 1
    for (int pr = 0; pr < 16; ++pr) {
      FC_SYNC();
      stage1(1);
      compute(0);
      FC_SYNC();
      if (pr < 15) stage1(0);
      compute(1);
    }
#undef FC_SYNC
#pragma unroll
    for (int fm = 0; fm < 4; ++fm) {
#pragma unroll
      for (int i = 0; i < 4; ++i) {
        const int m = m0 + wm * 64 + fm * 16 + quad * 4 + i;
        if (m >= 6000) continue;
#pragma unroll
        for (int fn = 0; fn < 4; ++fn) {
          const int n = n0 + wn * 64 + fn * 16 + l16;
          outF[(size_t)m * 1024 + n] = acc[fm][fn][i] + bias[n];
        }
      }
    }
  }
}

// ---------------- fused attention v12 (unchanged, 89.6 us) ----------------
__global__ __launch_bounds__(256, 4) void attn_kernel(const u16* __restrict__ qkv,
                                                      const u16* __restrict__ Vt,
                                                      const u16* __restrict__ poskbf,
                                                      const u16* __restrict__ posvT,
                                                      const float* __restrict__ posv,
                                                      u16* __restrict__ hidden) {
  const size_t ZS = 4UL * 16 * 1536 * 64;
  __shared__ u16 qb_s[64 * 136];    // merged: qp[q][r] (prologue) -> P histogram [q][delta]
  __shared__ u16 kbuf[2][2048];     // K tile 32 rows x 64 d (row-permuted + chunk-swizzled), dbuf
  __shared__ u16 vbuf[2][2048];     // V^T tile 64 d x 32 k (chunk-swizzled), dbuf

  const int tid = threadIdx.x;
  const int w = tid >> 6, lane = tid & 63, quad = lane >> 4, l16 = lane & 15;
  const int bi = blockIdx.x;
  const int bh = bi & 63;
  const int q0 = (bi >> 6) * 64, qw0 = q0 + w * 16;
  const int b = bh >> 4;
  const size_t sb = (size_t)bh * (1536UL * 64UL);
  const u16* Qp = qkv + sb;
  const u16* Kp = qkv + ZS + sb;
  const u16* Vtb = Vt + (size_t)bh * (64UL * 1536UL);
  u16* qb_row = qb_s + (w * 16 + l16) * 136;   // this lane's row (q = qw0 + l16)

  // staging: wave-uniform LDS base + lane*16B (gll16 contract)
  const int r8 = lane >> 3, c8 = lane & 7;            // K: 8 rows x 8 chunks
  const int vr = lane >> 2, vc = lane & 3;            // V: 16 rows x 4 chunks
  // K row permutation: LDS row p <- global row kp(p) = quad(p)*8 + cg(p)*4 + i(p)
  const int kprow = ((( (w * 8 + r8) & 15) >> 2) * 8) + (((w * 8 + r8) >> 4) * 4) + ((w * 8 + r8) & 3);
  // induction source pointers (advance +2048 / +32 u16 per k-tile)
  const u16* kSrc = Kp + (size_t)kprow * 64 + ((c8 ^ r8) * 8);
  const u16* vSrc = Vtb + (size_t)(w * 16 + vr) * 1536 + ((vc ^ ((vr >> 1) & 3)) * 8);
  u16* const kDst = &kbuf[0][0] + w * 512;   // +2048 for buf1
  u16* const vDst = &vbuf[0][0] + w * 512;

  gll16(kSrc, kDst);
  gll16(vSrc, vDst);

  // Q fragment (rows q = qw0 + l16)
  const u16* qptr = Qp + (size_t)(qw0 + l16) * 64 + quad * 8;
  const bf16x8 qB0 = *(const bf16x8*)qptr;
  const bf16x8 qB1 = *(const bf16x8*)(qptr + 32);

  // qp[q][r] = q . pos_k[r] via MFMA; C layout: row q_loc = quad*4+i, col r = l16
  const f32x4 zf = {0.f, 0.f, 0.f, 0.f};
#pragma unroll
  for (int nf = 0; nf < 9; ++nf) {
    const u16* bp = poskbf + (size_t)(nf * 16 + l16) * 64 + quad * 8;
    bf16x8 b0 = *(const bf16x8*)bp;
    bf16x8 b1 = *(const bf16x8*)(bp + 32);
    f32x4 c = zf;
    c = MFMA16(qB0, b0, c);
    c = MFMA16(qB1, b1, c);
    const int col = nf * 16 + l16;
    if (col < 136) {
#pragma unroll
      for (int i = 0; i < 4; ++i)
        qb_s[(w * 16 + quad * 4 + i) * 136 + col] = f2bf(c[i]);
    }
  }
  __syncthreads();   // qp ready AND buf0 DMA drained

  const float L2E = 1.44269504f;
  const float M8 = -8.0f * L2E;
  const float eLow  = __builtin_fmaf(bf2f(qb_row[0]), L2E, M8);
  const float eHigh = __builtin_fmaf(bf2f(qb_row[128]), L2E, M8);

  f32x4 accf[4];
#pragma unroll
  for (int dc = 0; dc < 4; ++dc) accf[dc] = zf;
  float sSimple = 0.f, sLowSave = 0.f, sDall = 0.f, sD0 = 0.f, sD128 = 0.f;

  const int itLowEnd = (qw0 >= 95) ? (((qw0 - 95) >> 5) + 1) : 0;
  const int itHigh0 = (qw0 + 110) >> 5;
  const int dEnd = itHigh0 < 46 ? itHigh0 : 46;

  const int kswz = (quad ^ (l16 & 7)) * 8;
  const int kswz4 = ((quad + 4) ^ (l16 & 7)) * 8;
  const int vpos = (quad ^ ((l16 >> 1) & 3)) * 8;   // V chunk position after swizzle

  // stage source cursors point at tile it+1
  const u16* kS = kSrc + 2048;
  const u16* vS = vSrc + 32;

  // loop body; kb/vbse/doStage/stageOff are compile-time per call site -> fragment
  // addresses hoist, no runtime buffer select.
  auto body = [&](int it, const u16* kb, const u16* vbse, bool doStage, int stageOff) {
    if (doStage) {
      gll16(kS, kDst + stageOff);
      gll16(vS, vDst + stageOff);
      kS += 2048; vS += 32;
    }

    if (it == itLowEnd) sLowSave = sSimple;
    const int phase = (it < itLowEnd) ? 0 : ((it >= 46) ? 1 : ((it < dEnd) ? 1 : 2));

    // K fragments (row-permuted + chunk-swizzled, conflict-free)
    bf16x8 ka00 = *(const bf16x8*)(kb + l16 * 64 + kswz);
    bf16x8 ka01 = *(const bf16x8*)(kb + l16 * 64 + kswz4);
    bf16x8 ka10 = *(const bf16x8*)(kb + (16 + l16) * 64 + kswz);
    bf16x8 ka11 = *(const bf16x8*)(kb + (16 + l16) * 64 + kswz4);
    // V^T fragments (chunk-swizzled, conflict-free)
    bf16x8 vb0 = *(const bf16x8*)(vbse + l16 * 32 + vpos);
    bf16x8 vb1 = *(const bf16x8*)(vbse + (16 + l16) * 32 + vpos);
    bf16x8 vb2 = *(const bf16x8*)(vbse + (32 + l16) * 32 + vpos);
    bf16x8 vb3 = *(const bf16x8*)(vbse + (48 + l16) * 32 + vpos);

    // diag bias LDS reads (index-only dependence); permuted k: delta = base + quad*8 + cg*4 + i
    float qb[2][4];
    if (phase == 1) {
      const int base = it * 32 + 64 - qw0 - l16 + quad * 8;
#pragma unroll
      for (int cg = 0; cg < 2; ++cg) {
#pragma unroll
        for (int i = 0; i < 4; ++i) {
          int delta = base + cg * 4 + i;
          delta = delta < 0 ? 0 : (delta > 128 ? 128 : delta);
          qb[cg][i] = bf2f(qb_row[delta]);
        }
      }
    }

    f32x4 cc[2];
    cc[0] = zf; cc[1] = zf;
    cc[0] = MFMA16(ka00, qB0, cc[0]);
    cc[0] = MFMA16(ka01, qB1, cc[0]);
    cc[1] = MFMA16(ka10, qB0, cc[1]);
    cc[1] = MFMA16(ka11, qB1, cc[1]);

    float pvv[2][4];
    if (phase != 1) {
      const float eB = (phase == 0) ? eLow : eHigh;
#pragma unroll
      for (int cg = 0; cg < 2; ++cg) {
#pragma unroll
        for (int i = 0; i < 4; ++i) {
          float p = __builtin_amdgcn_exp2f(__builtin_fmaf(cc[cg][i], L2E, eB));
          sSimple += p; pvv[cg][i] = p;
        }
      }
    } else {
      const int kc0 = it * 32;
#pragma unroll
      for (int cg = 0; cg < 2; ++cg) {
        const int krow0 = kc0 + quad * 8 + cg * 4;            // actual k base (permuted)
        const int dbase = krow0 + 64 - qw0 - l16;
#pragma unroll
        for (int i = 0; i < 4; ++i) {
          int delta = dbase + i;
          delta = delta < 0 ? 0 : (delta > 128 ? 128 : delta);
          const float t = cc[cg][i] + qb[cg][i];
          float p = __builtin_amdgcn_exp2f(__builtin_fmaf(t, L2E, M8));
          if (krow0 + i >= 1500) p = 0.f;
          sDall += p;
          sD0   += (delta == 0)   ? p : 0.f;
          sD128 += (delta == 128) ? p : 0.f;
          pvv[cg][i] = p;
        }
        // packed bf16 P stores into the merged buffer (deltas 1..127 only)
        const uint pk01 = cvt_pk_bf16(pvv[cg][0], pvv[cg][1]);
        const uint pk23 = cvt_pk_bf16(pvv[cg][2], pvv[cg][3]);
        const u16 hb[4] = {(u16)pk01, (u16)(pk01 >> 16), (u16)pk23, (u16)(pk23 >> 16)};
#pragma unroll
        for (int i = 0; i < 4; ++i) {
          int delta = dbase + i;
          delta = delta < 0 ? 0 : (delta > 128 ? 128 : delta);
          if ((delta != 0) & (delta != 128)) qb_row[delta] = hb[i];
        }
      }
    }

    // P already in A-fragment order (k = quad*8 + cg*4 + i): just pack to bf16
    union { uint u[4]; bf16x8 v; } pa;
    pa.u[0] = cvt_pk_bf16(pvv[0][0], pvv[0][1]);
    pa.u[1] = cvt_pk_bf16(pvv[0][2], pvv[0][3]);
    pa.u[2] = cvt_pk_bf16(pvv[1][0], pvv[1][1]);
    pa.u[3] = cvt_pk_bf16(pvv[1][2], pvv[1][3]);

    accf[0] = MFMA16(pa.v, vb0, accf[0]);
    accf[1] = MFMA16(pa.v, vb1, accf[1]);
    accf[2] = MFMA16(pa.v, vb2, accf[2]);
    accf[3] = MFMA16(pa.v, vb3, accf[3]);

    __syncthreads();   // drains next-buffer DMA; guards buffer turnover
  };

#pragma unroll 1
  for (int pr = 0; pr < 23; ++pr) {
    const int it0 = pr * 2;
    body(it0,     &kbuf[0][0], &vbuf[0][0], true, 2048);   // cur=0, stage -> buf1
    body(it0 + 1, &kbuf[1][0], &vbuf[1][0], true, 0);      // cur=1, stage -> buf0
  }
  body(46, &kbuf[0][0], &vbuf[0][0], false, 0);

  // reduce softmax state over the 4 quads (q = l16 per lane)
  const float sLow = sLowSave;
  const float sHigh = sSimple - sLowSave;
  float lpart = sSimple + sDall;
  float clow = sLow + sD0;
  float chigh = sHigh + sD128;
#pragma unroll
  for (int m = 16; m <= 32; m <<= 1) {
    lpart += __shfl_xor(lpart, m);
    clow  += __shfl_xor(clow, m);
    chigh += __shfl_xor(chigh, m);
  }
  const float linv = 1.0f / lpart;

  // merged-buffer fixup (wave-private): zero slots the diag pass never wrote so the
  // o2 MFMA sees P=0 there. Row qg: visited slots = [64-qg, 1563-qg] ∩ [1,127];
  // slot 0 always holds qp[0] and must be zeroed. Middle q-tiles: no loop work.
  {
    const int qg_row = qw0 + l16;
    if (quad == 0) qb_row[0] = 0;
    const int lim = 64 - qg_row;              // zero d in [1, lim)
    for (int d = 1 + quad; d < lim; d += 4) qb_row[d] = 0;
    const int dlo = 1564 - qg_row;            // zero d in [dlo, 127]
    for (int d = dlo + quad; d <= 127; d += 4) qb_row[d] = 0;
  }

  // o2 = P[16x128] @ pos_v[128x64] via MFMA (rows wave-private; no barrier needed)
  f32x4 o2[4];
#pragma unroll
  for (int dc = 0; dc < 4; ++dc) o2[dc] = zf;
#pragma unroll
  for (int kk = 0; kk < 4; ++kk) {
    bf16x8 pa2 = *(const bf16x8*)(qb_row + kk * 32 + quad * 8);
#pragma unroll
    for (int dc = 0; dc < 4; ++dc) {
      bf16x8 vb2r = *(const bf16x8*)(posvT + (size_t)(dc * 16 + l16) * 136 + kk * 32 + quad * 8);
      o2[dc] = MFMA16(pa2, vb2r, o2[dc]);
    }
  }

  // per-q scalars live at lane l16=q_loc after butterfly -> shfl from lane q_loc
  float li[4], cl[4], ch[4];
#pragma unroll
  for (int i = 0; i < 4; ++i) {
    const int srcl = quad * 4 + i;
    li[i] = __shfl(linv, srcl);
    cl[i] = __shfl(clow, srcl);
    ch[i] = __shfl(chigh, srcl);
  }

#pragma unroll
  for (int dc = 0; dc < 4; ++dc) {
    const int d = dc * 16 + l16;
    const float pv0 = posv[d], pv1 = posv[128 * 64 + d];
#pragma unroll
    for (int i = 0; i < 4; ++i) {
      const int qg = qw0 + quad * 4 + i;
      if (qg < 1500) {
        const float val = (accf[dc][i] + o2[dc][i] + cl[i] * pv0 + ch[i] * pv1) * li[i];
        hidden[((size_t)(b * 1500 + qg)) * 1024 + (bh & 15) * 64 + d] = f2bf(val);
      }
    }
  }
}

// ---------------- launcher ----------------
extern "C" void kernel_launch(void* const* d_in, const int* in_sizes, int n_in,
                              void* d_out, int out_size, void* d_ws, size_t ws_size,
                              hipStream_t stream) {
  const float* query = (const float*)d_in[0];
  const float* key   = (const float*)d_in[1];
  const float* value = (const float*)d_in[2];
  const float* Wq = (const float*)d_in[3];
  const float* bq = (const float*)d_in[4];
  const float* Wk = (const float*)d_in[5];
  const float* bk = (const float*)d_in[6];
  const float* Wv = (const float*)d_in[7];
  const float* bv = (const float*)d_in[8];
  const float* posk = (const float*)d_in[9];
  const float* posv = (const float*)d_in[10];
  const float* Wfc = (const float*)d_in[11];
  const float* bfc = (const float*)d_in[12];
  float* out = (float*)d_out;

  char* p = (char*)d_ws;
  u16* X = (u16*)p;        p += 3UL * 6016 * 1024 * 2;   // hidden + Vt live here
  u16* Wt = (u16*)p;       p += 3UL * 1024 * 1024 * 2;   // Wq_t,Wk_t,Wv_t
  u16* Wfct = (u16*)p;     p += 1024UL * 1024 * 2;
  u16* poskbf = (u16*)p;   p += 144UL * 64 * 2;
  u16* posvT = (u16*)p;    p += 64UL * 136 * 2;
  float* biascat = (float*)p; p += 3UL * 1024 * 4;
  u16* qkv = (u16*)p;      p += 3UL * 4 * 16 * 1536 * 64 * 2;  // q,k slabs used (v slab idle)
  u16* hidden = X;                       // [6016][1024] bf16
  u16* Vt = X + 6291456;                 // [64*64][1536] bf16

  pack_w_kernel<<<dim3(1025), 256, 0, stream>>>(Wq, Wk, Wv, Wfc, bq, bk, bv, posk, posv,
                                                Wt, Wfct, biascat, poskbf, posvT);

  gemm_bt_kernel<<<dim3(8, 47, 3), 256, 0, stream>>>(
      query, key, value, nullptr, Wt, 1024L * 1024, biascat, 1024L, qkv, Vt, nullptr, 0);

  attn_kernel<<<dim3(1536), 256, 0, stream>>>(qkv, Vt, poskbf, posvT, posv, hidden);

  gemm_bt_kernel<<<dim3(8, 47, 1), 256, 0, stream>>>(
      nullptr, nullptr, nullptr, hidden, Wfct, 0L, bfc, 0L, nullptr, nullptr, out, 1);
}

// Round 12
// 332.302 us; speedup vs baseline: 1.1214x; 1.0419x over previous
//
#include <hip/hip_runtime.h>
#include <stdint.h>

typedef unsigned short u16;
typedef __attribute__((ext_vector_type(8))) short bf16x8;
typedef __attribute__((ext_vector_type(4))) float f32x4;

#define MFMA16(a, b, c) __builtin_amdgcn_mfma_f32_16x16x32_bf16(a, b, c, 0, 0, 0)

__device__ __forceinline__ u16 f2bf(float x) {
  union { float f; uint32_t u; } v; v.f = x;
  uint32_t r = (v.u + 0x7FFFu + ((v.u >> 16) & 1u)) >> 16;
  return (u16)r;
}
__device__ __forceinline__ float bf2f(u16 h) {
  union { uint32_t u; float f; } v; v.u = ((uint32_t)h) << 16; return v.f;
}
// packed RNE f32x2 -> bf16x2 (gfx942+ VOP3; low16 = a, high16 = b)
__device__ __forceinline__ uint cvt_pk_bf16(float a, float b) {
  uint r;
  asm("v_cvt_pk_bf16_f32 %0, %1, %2" : "=v"(r) : "v"(a), "v"(b));
  return r;
}
__device__ __forceinline__ void gll16(const void* g, void* s) {
  __builtin_amdgcn_global_load_lds((const __attribute__((address_space(1))) unsigned int*)g,
                                   (__attribute__((address_space(3))) unsigned int*)s, 16, 0, 0);
}

// ---------------- pack kernels ----------------

// merged weight/misc pack, grid 1025 blocks:
//  [0,768):    Wt[z][(n*64+d)*1024 + h] = W[z][n][h][d]
//  [768,1024): Wfct[o*1024 + i] = Wfc[i*1024 + o]
//  1024:       bias concat + pos_k bf16 (144 rows) + pos_v^T bf16 (64x136)
__global__ __launch_bounds__(256) void pack_w_kernel(const float* __restrict__ Wq,
                                                     const float* __restrict__ Wk,
                                                     const float* __restrict__ Wv,
                                                     const float* __restrict__ Wfc,
                                                     const float* __restrict__ bq,
                                                     const float* __restrict__ bk,
                                                     const float* __restrict__ bv,
                                                     const float* __restrict__ posk,
                                                     const float* __restrict__ posv,
                                                     u16* __restrict__ Wt,
                                                     u16* __restrict__ Wfct,
                                                     float* __restrict__ biascat,
                                                     u16* __restrict__ poskbf,
                                                     u16* __restrict__ posvT) {
  __shared__ float tile[64][65];
  const int bi = blockIdx.x;
  if (bi == 1024) {
    for (int i = threadIdx.x; i < 1024; i += 256) {
      biascat[i] = bq[i]; biascat[1024 + i] = bk[i]; biascat[2048 + i] = bv[i];
    }
    for (int i = threadIdx.x; i < 144 * 64; i += 256) {
      int r = i >> 6;
      poskbf[i] = (r < 129) ? f2bf(posk[i]) : (u16)0;
    }
    const int d = threadIdx.x & 63, rr = threadIdx.x >> 6;
#pragma unroll
    for (int j = 0; j < 34; ++j) {
      const int r = rr * 34 + j;
      posvT[d * 136 + r] = (r < 129) ? f2bf(posv[(size_t)r * 64 + d]) : (u16)0;
    }
    return;
  }
  const int r = threadIdx.x >> 2, c0 = (threadIdx.x & 3) * 16;
  const float* src;
  u16* outp;
  if (bi < 768) {
    const int z = bi >> 8, rem = bi & 255, n = rem >> 4, h0 = (rem & 15) * 64;
    const float* W = z == 0 ? Wq : (z == 1 ? Wk : Wv);
    src = W + (size_t)n * 65536 + (size_t)(h0 + r) * 64 + c0;
    outp = Wt + (size_t)z * (1024UL * 1024UL) + (size_t)(n * 64 + r) * 1024 + h0 + c0;
  } else {
    const int t = bi - 768;
    const int i0 = (t & 15) * 64, o0 = (t >> 4) * 64;
    src = Wfc + (size_t)(i0 + r) * 1024 + o0 + c0;
    outp = Wfct + (size_t)(o0 + r) * 1024 + i0 + c0;
  }
#pragma unroll
  for (int j = 0; j < 16; j += 4) {
    float4 f = *(const float4*)(src + j);
    tile[r][c0 + j] = f.x; tile[r][c0 + j + 1] = f.y;
    tile[r][c0 + j + 2] = f.z; tile[r][c0 + j + 3] = f.w;
  }
  __syncthreads();
#pragma unroll
  for (int j = 0; j < 16; ++j) outp[j] = f2bf(tile[c0 + j][r]);
}

// ---------------- GEMM v17 (QKV only): fused pack_x + vtrans, early A-issue ----------
// A read DIRECTLY from fp32 query/key/value, ONE register set; loadA(t+1) issued
// right after wrA(t) so barrier-wait + gllB + compute cover its latency.
// z==0/1 write qkv[bh][1536][64]; z==2 writes Vt directly via LDS-transposed epilogue.
// LDS: smem[17408] u16 = 34816 B (loop: bufA 2x4096 + bufB 2x4096; epi: T 128x136).
__global__ __launch_bounds__(256, 4) void gemm_bt_kernel(
    const float* __restrict__ aQ, const float* __restrict__ aK, const float* __restrict__ aV,
    const u16* __restrict__ Bbase, long bStride,
    const float* __restrict__ biasBase, long biasStride,
    u16* __restrict__ outBF, u16* __restrict__ VtOut) {
  __shared__ u16 smem[17408];   // As: [buf*4096], Bs: [8192+buf*4096], T: [0..17407]

  // XCD-aware bijective swizzle of the 3D grid (x=8 n-tiles fastest, y=47 m, z)
  const int nwg = 376 * gridDim.z;           // 1128
  const int cpx = nwg >> 3;
  const int lid = blockIdx.x + (blockIdx.y << 3) + blockIdx.z * 376;
  const int swz = (lid & 7) * cpx + (lid >> 3);
  const int z = swz / 376;
  const int rem = swz - z * 376;
  const int m0 = (rem >> 3) * 128, n0 = (rem & 7) * 128;

  const u16* Bt = Bbase + (size_t)z * bStride;
  const float* bias = biasBase + (size_t)z * biasStride;
  const int tid = threadIdx.x, w = tid >> 6, lane = tid & 63;
  const int quad = lane >> 4, l16 = lane & 15;
  const int wm = w >> 1, wn = w & 1;
  const int srow = w * 16 + (lane >> 2);
  const int scol = (lane & 3) * 8;

  // B source induction pointers
  const u16* gB0 = Bt + (size_t)(n0 + srow) * 1024 + scol;
  const u16* gB1 = gB0 + 64UL * 1024;
  const int slab = (w * 16) * 32;            // wave's LDS slab offset (u16)

  f32x4 acc[4][4];
  const f32x4 zf = {0.f, 0.f, 0.f, 0.f};
#pragma unroll
  for (int a = 0; a < 4; ++a)
#pragma unroll
    for (int b = 0; b < 4; ++b) acc[a][b] = zf;

  auto gllB = [&](int buf) {
    gll16(gB0, &smem[8192 + buf * 4096 + slab]);
    gll16(gB1, &smem[8192 + buf * 4096 + slab + 64 * 32]);
    gB0 += 32; gB1 += 32;
  };
  auto compute = [&](int buf) {
    bf16x8 af[4], bfr[4];
#pragma unroll
    for (int f = 0; f < 4; ++f) {
      af[f]  = *(const bf16x8*)&smem[buf * 4096 + (wm * 64 + f * 16 + l16) * 32 + quad * 8];
      bfr[f] = *(const bf16x8*)&smem[8192 + buf * 4096 + (wn * 64 + f * 16 + l16) * 32 + quad * 8];
    }
#pragma unroll
    for (int fm = 0; fm < 4; ++fm)
#pragma unroll
      for (int fn = 0; fn < 4; ++fn)
        acc[fm][fn] = MFMA16(af[fm], bfr[fn], acc[fm][fn]);
  };

  // ---- fp32 A path (fused pack_x), single reg set, early issue after wrA ----
  const float* srcF = z == 0 ? aQ : (z == 1 ? aK : aV);
  int rowA0 = m0 + srow;        if (rowA0 > 5999) rowA0 = 5999;
  int rowA1 = m0 + 64 + srow;   if (rowA1 > 5999) rowA1 = 5999;
  const float* fA0 = srcF + (size_t)rowA0 * 1024 + scol;
  const float* fA1 = srcF + (size_t)rowA1 * 1024 + scol;
  float4 a00, a01, a10, a11;
  auto loadA = [&]() {
    a00 = *(const float4*)fA0; a01 = *(const float4*)(fA0 + 4);
    a10 = *(const float4*)fA1; a11 = *(const float4*)(fA1 + 4);
    fA0 += 32; fA1 += 32;
  };
  const int adst = (w * 16 + (lane >> 2)) * 32 + (lane & 3) * 8;
  auto wrA = [&](int buf) {
    uint4 lo, hi;
    lo.x = cvt_pk_bf16(a00.x, a00.y); lo.y = cvt_pk_bf16(a00.z, a00.w);
    lo.z = cvt_pk_bf16(a01.x, a01.y); lo.w = cvt_pk_bf16(a01.z, a01.w);
    hi.x = cvt_pk_bf16(a10.x, a10.y); hi.y = cvt_pk_bf16(a10.z, a10.w);
    hi.z = cvt_pk_bf16(a11.x, a11.y); hi.w = cvt_pk_bf16(a11.z, a11.w);
    *(uint4*)&smem[buf * 4096 + adst] = lo;
    *(uint4*)&smem[buf * 4096 + adst + 64 * 32] = hi;
  };

  loadA();          // A(0) -> regs
  gllB(0);          // B(0) -> bufB0

#pragma unroll 1
  for (int pr = 0; pr < 16; ++pr) {
    // ---- t = 2pr (compute buf0) ----
    asm volatile("s_waitcnt vmcnt(0)" ::: "memory");
    __builtin_amdgcn_sched_barrier(0);
    wrA(0);                                           // A(2pr) -> bufA0
    loadA();                                          // A(2pr+1) (early issue)
    asm volatile("s_waitcnt lgkmcnt(0)" ::: "memory");
    __builtin_amdgcn_sched_barrier(0);
    __builtin_amdgcn_s_barrier();
    __builtin_amdgcn_sched_barrier(0);
    gllB(1);                                          // B(2pr+1) -> bufB1
    compute(0);
    // ---- t = 2pr+1 (compute buf1) ----
    asm volatile("s_waitcnt vmcnt(0)" ::: "memory");
    __builtin_amdgcn_sched_barrier(0);
    wrA(1);                                           // A(2pr+1) -> bufA1
    if (pr < 15) loadA();                             // A(2pr+2) (early issue)
    asm volatile("s_waitcnt lgkmcnt(0)" ::: "memory");
    __builtin_amdgcn_sched_barrier(0);
    __builtin_amdgcn_s_barrier();
    __builtin_amdgcn_sched_barrier(0);
    if (pr < 15) gllB(0);                             // B(2pr+2) -> bufB0
    compute(1);
  }

  if (z < 2) {
    const float scale = (z == 0) ? 0.125f : 1.0f;
    u16* out = outBF + (size_t)z * (4UL * 16 * 1536 * 64);
#pragma unroll
    for (int fm = 0; fm < 4; ++fm) {
#pragma unroll
      for (int i = 0; i < 4; ++i) {
        const int m = m0 + wm * 64 + fm * 16 + quad * 4 + i;
        if (m >= 6000) continue;
        const int bb = m / 1500;
        const int s = m - bb * 1500;
#pragma unroll
        for (int fn = 0; fn < 4; ++fn) {
          const int n = n0 + wn * 64 + fn * 16 + l16;
          const float vv = (acc[fm][fn][i] + bias[n]) * scale;
          const int h = n >> 6, d = n & 63;
          out[((size_t)(bb * 16 + h) * 1536 + s) * 64 + d] = f2bf(vv);
        }
      }
    }
  } else {
    // ---- fused vtrans: write Vt[(bb*16+h)*64+d][1536] via LDS transpose ----
    __syncthreads();   // all waves done with staging LDS
    u16* T = smem;     // [128][136] u16: T[n_local][m_local]
#pragma unroll
    for (int fm = 0; fm < 4; ++fm) {
      const int ml = wm * 64 + fm * 16 + quad * 4;
#pragma unroll
      for (int fn = 0; fn < 4; ++fn) {
        const int nl = wn * 64 + fn * 16 + l16;
        const float b0 = bias[n0 + nl];
        uint2 pk;
        pk.x = cvt_pk_bf16(acc[fm][fn][0] + b0, acc[fm][fn][1] + b0);
        pk.y = cvt_pk_bf16(acc[fm][fn][2] + b0, acc[fm][fn][3] + b0);
        *(uint2*)&T[nl * 136 + ml] = pk;
      }
    }
    __syncthreads();
#pragma unroll 1
    for (int ps = 0; ps < 8; ++ps) {
      const int row = ps * 16 + (tid >> 4);     // n_local
      const int col = (tid & 15) * 8;           // m_local base
      const int ng = n0 + row;
      const int h = ng >> 6, d = ng & 63;
      const int mg = m0 + col;
      uint4 v = *(const uint4*)&T[row * 136 + col];
      const int bb0 = mg / 1500, bb7 = (mg + 7) / 1500;
      if ((bb0 == bb7) & (mg + 7 < 6000)) {
        u16* dst = VtOut + ((size_t)((bb0 * 16 + h) * 64 + d)) * 1536 + (mg - bb0 * 1500);
        uint2 loh; loh.x = v.x; loh.y = v.y;
        uint2 hih; hih.x = v.z; hih.y = v.w;
        *(uint2*)dst = loh;
        *(uint2*)(dst + 4) = hih;
      } else {
        const u16* tv = (const u16*)&v;
#pragma unroll
        for (int j = 0; j < 8; ++j) {
          const int m = mg + j;
          if (m < 6000) {
            const int bb = m / 1500;
            VtOut[((size_t)((bb * 16 + h) * 64 + d)) * 1536 + (m - bb * 1500)] = tv[j];
          }
        }
      }
    }
  }
}

// ---------------- FC GEMM v18: 4-buffer depth-3 counted-vmcnt pipeline ----------------
// out[m][n] = hidden[m][k] . Wfct[n][k] + bfc[n], fp32 out. Grid (8,47) = 376 blocks
// = 1.47 blocks/CU -- grid-limited, so per-iter latency is fully exposed under the old
// vmcnt(0)-drain loop (~110-130us inferred by ledger). Fix: both operands are pure DMA
// (zero register cost), so stage 3 tiles ahead: prologue stages 0,1,2; per iter
// {vmcnt(8): tile t landed, t+1/t+2 in flight; barrier; stage(t+3); compute(t%4)}.
// Tail t=28..31: stage s31 at t=28, waits 8/8/4/0. Hazard: stage(t+3) writes buf
// (t-1)%4, whose last reader compute(t-1) is behind barrier(t). LDS 64KB (2 blocks/CU
// >= grid's 1.47). 32 iters % 4 == 0 -> all buffer indices compile-time.
__global__ __launch_bounds__(256, 2) void fc_kernel(const u16* __restrict__ Ahid,
                                                    const u16* __restrict__ Bt,
                                                    const float* __restrict__ bias,
                                                    float* __restrict__ outF) {
  __shared__ u16 As[4][4096];
  __shared__ u16 Bs[4][4096];

  // XCD-aware bijective swizzle (nwg = 376, %8 == 0)
  const int lid = blockIdx.x + (blockIdx.y << 3);
  const int swz = (lid & 7) * 47 + (lid >> 3);
  const int m0 = (swz >> 3) * 128, n0 = (swz & 7) * 128;

  const int tid = threadIdx.x, w = tid >> 6, lane = tid & 63;
  const int quad = lane >> 4, l16 = lane & 15;
  const int wm = w >> 1, wn = w & 1;
  const int srow = w * 16 + (lane >> 2);
  const int scol = (lane & 3) * 8;

  const u16* gA0 = Ahid + (size_t)(m0 + srow) * 1024 + scol;
  const u16* gA1 = gA0 + 64UL * 1024;
  const u16* gB0 = Bt + (size_t)(n0 + srow) * 1024 + scol;
  const u16* gB1 = gB0 + 64UL * 1024;
  const int slab = w * 512;

  f32x4 acc[4][4];
  const f32x4 zf = {0.f, 0.f, 0.f, 0.f};
#pragma unroll
  for (int a = 0; a < 4; ++a)
#pragma unroll
    for (int b = 0; b < 4; ++b) acc[a][b] = zf;

  auto stage = [&](int buf) {
    gll16(gA0, &As[buf][slab]);
    gll16(gA1, &As[buf][slab + 2048]);
    gll16(gB0, &Bs[buf][slab]);
    gll16(gB1, &Bs[buf][slab + 2048]);
    gA0 += 32; gA1 += 32; gB0 += 32; gB1 += 32;
  };
  auto compute = [&](int buf) {
    bf16x8 af[4], bfr[4];
#pragma unroll
    for (int f = 0; f < 4; ++f) {
      af[f]  = *(const bf16x8*)&As[buf][(wm * 64 + f * 16 + l16) * 32 + quad * 8];
      bfr[f] = *(const bf16x8*)&Bs[buf][(wn * 64 + f * 16 + l16) * 32 + quad * 8];
    }
#pragma unroll
    for (int fm = 0; fm < 4; ++fm)
#pragma unroll
      for (int fn = 0; fn < 4; ++fn)
        acc[fm][fn] = MFMA16(af[fm], bfr[fn], acc[fm][fn]);
  };

  stage(0); stage(1); stage(2);   // tiles 0..2 in flight

#define FC_BODY(BUF, N, DOSTAGE, SBUF) do {                   \
    asm volatile("s_waitcnt vmcnt(" #N ")" ::: "memory");     \
    __builtin_amdgcn_sched_barrier(0);                        \
    __builtin_amdgcn_s_barrier();                             \
    __builtin_amdgcn_sched_barrier(0);                        \
    if (DOSTAGE) stage(SBUF);                                 \
    compute(BUF);                                             \
  } while (0)

#pragma unroll 1
  for (int pr = 0; pr < 7; ++pr) {      // t = 4pr .. 4pr+3  (0..27), all steady
    FC_BODY(0, 8, true, 3);
    FC_BODY(1, 8, true, 0);
    FC_BODY(2, 8, true, 1);
    FC_BODY(3, 8, true, 2);
  }
  FC_BODY(0, 8, true, 3);               // t=28: stage s31
  FC_BODY(1, 8, false, 0);              // t=29
  FC_BODY(2, 4, false, 0);              // t=30
  FC_BODY(3, 0, false, 0);              // t=31
#undef FC_BODY

#pragma unroll
  for (int fm = 0; fm < 4; ++fm) {
#pragma unroll
    for (int i = 0; i < 4; ++i) {
      const int m = m0 + wm * 64 + fm * 16 + quad * 4 + i;
      if (m >= 6000) continue;
#pragma unroll
      for (int fn = 0; fn < 4; ++fn) {
        const int n = n0 + wn * 64 + fn * 16 + l16;
        outF[(size_t)m * 1024 + n] = acc[fm][fn][i] + bias[n];
      }
    }
  }
}

// ---------------- fused attention v12 (unchanged, 89.6 us) ----------------
__global__ __launch_bounds__(256, 4) void attn_kernel(const u16* __restrict__ qkv,
                                                      const u16* __restrict__ Vt,
                                                      const u16* __restrict__ poskbf,
                                                      const u16* __restrict__ posvT,
                                                      const float* __restrict__ posv,
                                                      u16* __restrict__ hidden) {
  const size_t ZS = 4UL * 16 * 1536 * 64;
  __shared__ u16 qb_s[64 * 136];    // merged: qp[q][r] (prologue) -> P histogram [q][delta]
  __shared__ u16 kbuf[2][2048];     // K tile 32 rows x 64 d (row-permuted + chunk-swizzled), dbuf
  __shared__ u16 vbuf[2][2048];     // V^T tile 64 d x 32 k (chunk-swizzled), dbuf

  const int tid = threadIdx.x;
  const int w = tid >> 6, lane = tid & 63, quad = lane >> 4, l16 = lane & 15;
  const int bi = blockIdx.x;
  const int bh = bi & 63;
  const int q0 = (bi >> 6) * 64, qw0 = q0 + w * 16;
  const int b = bh >> 4;
  const size_t sb = (size_t)bh * (1536UL * 64UL);
  const u16* Qp = qkv + sb;
  const u16* Kp = qkv + ZS + sb;
  const u16* Vtb = Vt + (size_t)bh * (64UL * 1536UL);
  u16* qb_row = qb_s + (w * 16 + l16) * 136;   // this lane's row (q = qw0 + l16)

  // staging: wave-uniform LDS base + lane*16B (gll16 contract)
  const int r8 = lane >> 3, c8 = lane & 7;            // K: 8 rows x 8 chunks
  const int vr = lane >> 2, vc = lane & 3;            // V: 16 rows x 4 chunks
  // K row permutation: LDS row p <- global row kp(p) = quad(p)*8 + cg(p)*4 + i(p)
  const int kprow = ((( (w * 8 + r8) & 15) >> 2) * 8) + (((w * 8 + r8) >> 4) * 4) + ((w * 8 + r8) & 3);
  // induction source pointers (advance +2048 / +32 u16 per k-tile)
  const u16* kSrc = Kp + (size_t)kprow * 64 + ((c8 ^ r8) * 8);
  const u16* vSrc = Vtb + (size_t)(w * 16 + vr) * 1536 + ((vc ^ ((vr >> 1) & 3)) * 8);
  u16* const kDst = &kbuf[0][0] + w * 512;   // +2048 for buf1
  u16* const vDst = &vbuf[0][0] + w * 512;

  gll16(kSrc, kDst);
  gll16(vSrc, vDst);

  // Q fragment (rows q = qw0 + l16)
  const u16* qptr = Qp + (size_t)(qw0 + l16) * 64 + quad * 8;
  const bf16x8 qB0 = *(const bf16x8*)qptr;
  const bf16x8 qB1 = *(const bf16x8*)(qptr + 32);

  // qp[q][r] = q . pos_k[r] via MFMA; C layout: row q_loc = quad*4+i, col r = l16
  const f32x4 zf = {0.f, 0.f, 0.f, 0.f};
#pragma unroll
  for (int nf = 0; nf < 9; ++nf) {
    const u16* bp = poskbf + (size_t)(nf * 16 + l16) * 64 + quad * 8;
    bf16x8 b0 = *(const bf16x8*)bp;
    bf16x8 b1 = *(const bf16x8*)(bp + 32);
    f32x4 c = zf;
    c = MFMA16(qB0, b0, c);
    c = MFMA16(qB1, b1, c);
    const int col = nf * 16 + l16;
    if (col < 136) {
#pragma unroll
      for (int i = 0; i < 4; ++i)
        qb_s[(w * 16 + quad * 4 + i) * 136 + col] = f2bf(c[i]);
    }
  }
  __syncthreads();   // qp ready AND buf0 DMA drained

  const float L2E = 1.44269504f;
  const float M8 = -8.0f * L2E;
  const float eLow  = __builtin_fmaf(bf2f(qb_row[0]), L2E, M8);
  const float eHigh = __builtin_fmaf(bf2f(qb_row[128]), L2E, M8);

  f32x4 accf[4];
#pragma unroll
  for (int dc = 0; dc < 4; ++dc) accf[dc] = zf;
  float sSimple = 0.f, sLowSave = 0.f, sDall = 0.f, sD0 = 0.f, sD128 = 0.f;

  const int itLowEnd = (qw0 >= 95) ? (((qw0 - 95) >> 5) + 1) : 0;
  const int itHigh0 = (qw0 + 110) >> 5;
  const int dEnd = itHigh0 < 46 ? itHigh0 : 46;

  const int kswz = (quad ^ (l16 & 7)) * 8;
  const int kswz4 = ((quad + 4) ^ (l16 & 7)) * 8;
  const int vpos = (quad ^ ((l16 >> 1) & 3)) * 8;   // V chunk position after swizzle

  // stage source cursors point at tile it+1
  const u16* kS = kSrc + 2048;
  const u16* vS = vSrc + 32;

  // loop body; kb/vbse/doStage/stageOff are compile-time per call site -> fragment
  // addresses hoist, no runtime buffer select.
  auto body = [&](int it, const u16* kb, const u16* vbse, bool doStage, int stageOff) {
    if (doStage) {
      gll16(kS, kDst + stageOff);
      gll16(vS, vDst + stageOff);
      kS += 2048; vS += 32;
    }

    if (it == itLowEnd) sLowSave = sSimple;
    const int phase = (it < itLowEnd) ? 0 : ((it >= 46) ? 1 : ((it < dEnd) ? 1 : 2));

    // K fragments (row-permuted + chunk-swizzled, conflict-free)
    bf16x8 ka00 = *(const bf16x8*)(kb + l16 * 64 + kswz);
    bf16x8 ka01 = *(const bf16x8*)(kb + l16 * 64 + kswz4);
    bf16x8 ka10 = *(const bf16x8*)(kb + (16 + l16) * 64 + kswz);
    bf16x8 ka11 = *(const bf16x8*)(kb + (16 + l16) * 64 + kswz4);
    // V^T fragments (chunk-swizzled, conflict-free)
    bf16x8 vb0 = *(const bf16x8*)(vbse + l16 * 32 + vpos);
    bf16x8 vb1 = *(const bf16x8*)(vbse + (16 + l16) * 32 + vpos);
    bf16x8 vb2 = *(const bf16x8*)(vbse + (32 + l16) * 32 + vpos);
    bf16x8 vb3 = *(const bf16x8*)(vbse + (48 + l16) * 32 + vpos);

    // diag bias LDS reads (index-only dependence); permuted k: delta = base + quad*8 + cg*4 + i
    float qb[2][4];
    if (phase == 1) {
      const int base = it * 32 + 64 - qw0 - l16 + quad * 8;
#pragma unroll
      for (int cg = 0; cg < 2; ++cg) {
#pragma unroll
        for (int i = 0; i < 4; ++i) {
          int delta = base + cg * 4 + i;
          delta = delta < 0 ? 0 : (delta > 128 ? 128 : delta);
          qb[cg][i] = bf2f(qb_row[delta]);
        }
      }
    }

    f32x4 cc[2];
    cc[0] = zf; cc[1] = zf;
    cc[0] = MFMA16(ka00, qB0, cc[0]);
    cc[0] = MFMA16(ka01, qB1, cc[0]);
    cc[1] = MFMA16(ka10, qB0, cc[1]);
    cc[1] = MFMA16(ka11, qB1, cc[1]);

    float pvv[2][4];
    if (phase != 1) {
      const float eB = (phase == 0) ? eLow : eHigh;
#pragma unroll
      for (int cg = 0; cg < 2; ++cg) {
#pragma unroll
        for (int i = 0; i < 4; ++i) {
          float p = __builtin_amdgcn_exp2f(__builtin_fmaf(cc[cg][i], L2E, eB));
          sSimple += p; pvv[cg][i] = p;
        }
      }
    } else {
      const int kc0 = it * 32;
#pragma unroll
      for (int cg = 0; cg < 2; ++cg) {
        const int krow0 = kc0 + quad * 8 + cg * 4;            // actual k base (permuted)
        const int dbase = krow0 + 64 - qw0 - l16;
#pragma unroll
        for (int i = 0; i < 4; ++i) {
          int delta = dbase + i;
          delta = delta < 0 ? 0 : (delta > 128 ? 128 : delta);
          const float t = cc[cg][i] + qb[cg][i];
          float p = __builtin_amdgcn_exp2f(__builtin_fmaf(t, L2E, M8));
          if (krow0 + i >= 1500) p = 0.f;
          sDall += p;
          sD0   += (delta == 0)   ? p : 0.f;
          sD128 += (delta == 128) ? p : 0.f;
          pvv[cg][i] = p;
        }
        // packed bf16 P stores into the merged buffer (deltas 1..127 only)
        const uint pk01 = cvt_pk_bf16(pvv[cg][0], pvv[cg][1]);
        const uint pk23 = cvt_pk_bf16(pvv[cg][2], pvv[cg][3]);
        const u16 hb[4] = {(u16)pk01, (u16)(pk01 >> 16), (u16)pk23, (u16)(pk23 >> 16)};
#pragma unroll
        for (int i = 0; i < 4; ++i) {
          int delta = dbase + i;
          delta = delta < 0 ? 0 : (delta > 128 ? 128 : delta);
          if ((delta != 0) & (delta != 128)) qb_row[delta] = hb[i];
        }
      }
    }

    // P already in A-fragment order (k = quad*8 + cg*4 + i): just pack to bf16
    union { uint u[4]; bf16x8 v; } pa;
    pa.u[0] = cvt_pk_bf16(pvv[0][0], pvv[0][1]);
    pa.u[1] = cvt_pk_bf16(pvv[0][2], pvv[0][3]);
    pa.u[2] = cvt_pk_bf16(pvv[1][0], pvv[1][1]);
    pa.u[3] = cvt_pk_bf16(pvv[1][2], pvv[1][3]);

    accf[0] = MFMA16(pa.v, vb0, accf[0]);
    accf[1] = MFMA16(pa.v, vb1, accf[1]);
    accf[2] = MFMA16(pa.v, vb2, accf[2]);
    accf[3] = MFMA16(pa.v, vb3, accf[3]);

    __syncthreads();   // drains next-buffer DMA; guards buffer turnover
  };

#pragma unroll 1
  for (int pr = 0; pr < 23; ++pr) {
    const int it0 = pr * 2;
    body(it0,     &kbuf[0][0], &vbuf[0][0], true, 2048);   // cur=0, stage -> buf1
    body(it0 + 1, &kbuf[1][0], &vbuf[1][0], true, 0);      // cur=1, stage -> buf0
  }
  body(46, &kbuf[0][0], &vbuf[0][0], false, 0);

  // reduce softmax state over the 4 quads (q = l16 per lane)
  const float sLow = sLowSave;
  const float sHigh = sSimple - sLowSave;
  float lpart = sSimple + sDall;
  float clow = sLow + sD0;
  float chigh = sHigh + sD128;
#pragma unroll
  for (int m = 16; m <= 32; m <<= 1) {
    lpart += __shfl_xor(lpart, m);
    clow  += __shfl_xor(clow, m);
    chigh += __shfl_xor(chigh, m);
  }
  const float linv = 1.0f / lpart;

  // merged-buffer fixup (wave-private): zero slots the diag pass never wrote so the
  // o2 MFMA sees P=0 there. Row qg: visited slots = [64-qg, 1563-qg] ∩ [1,127];
  // slot 0 always holds qp[0] and must be zeroed. Middle q-tiles: no loop work.
  {
    const int qg_row = qw0 + l16;
    if (quad == 0) qb_row[0] = 0;
    const int lim = 64 - qg_row;              // zero d in [1, lim)
    for (int d = 1 + quad; d < lim; d += 4) qb_row[d] = 0;
    const int dlo = 1564 - qg_row;            // zero d in [dlo, 127]
    for (int d = dlo + quad; d <= 127; d += 4) qb_row[d] = 0;
  }

  // o2 = P[16x128] @ pos_v[128x64] via MFMA (rows wave-private; no barrier needed)
  f32x4 o2[4];
#pragma unroll
  for (int dc = 0; dc < 4; ++dc) o2[dc] = zf;
#pragma unroll
  for (int kk = 0; kk < 4; ++kk) {
    bf16x8 pa2 = *(const bf16x8*)(qb_row + kk * 32 + quad * 8);
#pragma unroll
    for (int dc = 0; dc < 4; ++dc) {
      bf16x8 vb2r = *(const bf16x8*)(posvT + (size_t)(dc * 16 + l16) * 136 + kk * 32 + quad * 8);
      o2[dc] = MFMA16(pa2, vb2r, o2[dc]);
    }
  }

  // per-q scalars live at lane l16=q_loc after butterfly -> shfl from lane q_loc
  float li[4], cl[4], ch[4];
#pragma unroll
  for (int i = 0; i < 4; ++i) {
    const int srcl = quad * 4 + i;
    li[i] = __shfl(linv, srcl);
    cl[i] = __shfl(clow, srcl);
    ch[i] = __shfl(chigh, srcl);
  }

#pragma unroll
  for (int dc = 0; dc < 4; ++dc) {
    const int d = dc * 16 + l16;
    const float pv0 = posv[d], pv1 = posv[128 * 64 + d];
#pragma unroll
    for (int i = 0; i < 4; ++i) {
      const int qg = qw0 + quad * 4 + i;
      if (qg < 1500) {
        const float val = (accf[dc][i] + o2[dc][i] + cl[i] * pv0 + ch[i] * pv1) * li[i];
        hidden[((size_t)(b * 1500 + qg)) * 1024 + (bh & 15) * 64 + d] = f2bf(val);
      }
    }
  }
}

// ---------------- launcher ----------------
extern "C" void kernel_launch(void* const* d_in, const int* in_sizes, int n_in,
                              void* d_out, int out_size, void* d_ws, size_t ws_size,
                              hipStream_t stream) {
  const float* query = (const float*)d_in[0];
  const float* key   = (const float*)d_in[1];
  const float* value = (const float*)d_in[2];
  const float* Wq = (const float*)d_in[3];
  const float* bq = (const float*)d_in[4];
  const float* Wk = (const float*)d_in[5];
  const float* bk = (const float*)d_in[6];
  const float* Wv = (const float*)d_in[7];
  const float* bv = (const float*)d_in[8];
  const float* posk = (const float*)d_in[9];
  const float* posv = (const float*)d_in[10];
  const float* Wfc = (const float*)d_in[11];
  const float* bfc = (const float*)d_in[12];
  float* out = (float*)d_out;

  char* p = (char*)d_ws;
  u16* X = (u16*)p;        p += 3UL * 6016 * 1024 * 2;   // hidden + Vt live here
  u16* Wt = (u16*)p;       p += 3UL * 1024 * 1024 * 2;   // Wq_t,Wk_t,Wv_t
  u16* Wfct = (u16*)p;     p += 1024UL * 1024 * 2;
  u16* poskbf = (u16*)p;   p += 144UL * 64 * 2;
  u16* posvT = (u16*)p;    p += 64UL * 136 * 2;
  float* biascat = (float*)p; p += 3UL * 1024 * 4;
  u16* qkv = (u16*)p;      p += 3UL * 4 * 16 * 1536 * 64 * 2;  // q,k slabs used (v slab idle)
  u16* hidden = X;                       // [6016][1024] bf16
  u16* Vt = X + 6291456;                 // [64*64][1536] bf16

  pack_w_kernel<<<dim3(1025), 256, 0, stream>>>(Wq, Wk, Wv, Wfc, bq, bk, bv, posk, posv,
                                                Wt, Wfct, biascat, poskbf, posvT);

  gemm_bt_kernel<<<dim3(8, 47, 3), 256, 0, stream>>>(
      query, key, value, Wt, 1024L * 1024, biascat, 1024L, qkv, Vt);

  attn_kernel<<<dim3(1536), 256, 0, stream>>>(qkv, Vt, poskbf, posvT, posv, hidden);

  fc_kernel<<<dim3(8, 47), 256, 0, stream>>>(hidden, Wfct, bfc, out);
}